// Round 7
// baseline (326.459 us; speedup 1.0000x reference)
//
#include <hip/hip_runtime.h>
#include <hip/hip_bf16.h>

#define BDIM 1024
#define VDIM 6890
#define NJ   24
#define NCOL (VDIM*3)   // 20670
#define KPAD 224        // 207 padded to 7*32
#define NPAD 20736      // 108*192 = 81*256 columns, zero-padded for guardless loads
#define NB   8          // batches per k_lbs block (fallback path)
#define VPAD 6912       // 108*64 vertices, zero-padded for W fragments
#define MB   16         // batches per k_gemmlbs block (R6: halved for 2x occupancy)

// fp32-element offsets into d_out (float*):
#define OUT_VERTS   0
#define OUT_JPOSED  21166080
#define OUT_JREST   21239808
#define OUT_A       21313536
#define OUT_VSHAPED 21706752

// Fallback-path scratch inside the verts region of d_out (dead before k_lbs
// writes verts). Offsets in fp32 elements; pdt/pf are bf16 arrays.
#define SCRF_PDT    0          // bf16 NPAD*KPAD
#define SCRF_PF     2322432    // bf16 1024*224
#define SCRF_JTJS   2437120    // 792 f32

// Workspace layout (main fused path), byte offsets:
#define WSB_PDT   0u
#define WSB_PF    9289728u                    // NPAD*KPAD*2
#define WSB_JTJS  9748480u                    // + 1024*KPAD*2
#define WSB_WHI   9752064u                    // jtjs 3168 B, aligned up
#define WSB_WLO   10194432u                   // + VPAD*32*2
#define WSB_AHI   10636800u                   // + VPAD*32*2
#define WSB_ALO   11685376u                   // + 1024*512*2
#define WS_NEED   12733952u                   // + 1024*512*2

typedef __hip_bfloat16 bf16;
typedef unsigned short ushort_t;
typedef __attribute__((ext_vector_type(8))) short  short8;
typedef __attribute__((ext_vector_type(4))) float  float4v;

__device__ __forceinline__ bf16  tob(float x) { return __float2bfloat16(x); }

// RNE float->bf16 bit helpers (self-consistent hi/lo split; finite inputs only)
__device__ __forceinline__ ushort_t bf16_rne(float x) {
    unsigned u = __builtin_bit_cast(unsigned, x);
    unsigned r = (u + 0x7FFFu + ((u >> 16) & 1u)) >> 16;
    return (ushort_t)r;
}
__device__ __forceinline__ float bf16_to_f(ushort_t h) {
    unsigned u = ((unsigned)h) << 16;
    return __builtin_bit_cast(float, u);
}

// ---------------- Kernel P2: jtjs + wpack + posedirs-transpose in ONE launch ----------------
// These three jobs are mutually independent (inputs only). Fusing them lets the
// 24-block jtjs reduction (9% of CUs) run CONCURRENTLY with the 2268-block
// transpose instead of serializing ~60us of stream time into ~35.
// blocks [0,24): jtjs. [24,888): wpack (skipped if whi==null). [888,3156): transpose.
__global__ __launch_bounds__(256) void k_prep2(const float* __restrict__ jreg,
        const float* __restrict__ vt, const float* __restrict__ sd,
        const float* __restrict__ lbs, const float* __restrict__ pd,
        float* __restrict__ jtjs, ushort_t* __restrict__ whi,
        ushort_t* __restrict__ wlo, bf16* __restrict__ pdt) {
    __shared__ float red[4][33];
    __shared__ bf16 tile[32][65];
    int bid = blockIdx.x;
    int t = threadIdx.x;
    if (bid < 24) {
        // ---- jtjs: [JT|JS](24 x 33) = jreg(24 x V) @ [vt|sd](V x 33) ----
        int j = bid;
        float acc[33];
#pragma unroll
        for (int i = 0; i < 33; i++) acc[i] = 0.f;
        for (int v = t; v < VDIM; v += 256) {
            float r = jreg[j*VDIM + v];
#pragma unroll
            for (int m = 0; m < 3; m++) {
                acc[m] += r * vt[v*3+m];
#pragma unroll
                for (int l = 0; l < 10; l++)
                    acc[3 + m*10 + l] += r * sd[(v*3+m)*10 + l];
            }
        }
        int lane = t & 63, wid = t >> 6;
#pragma unroll
        for (int i = 0; i < 33; i++) {
            float x = acc[i];
            for (int off = 32; off > 0; off >>= 1) x += __shfl_down(x, off);
            if (lane == 0) red[wid][i] = x;
        }
        __syncthreads();
        if (t < 33)
            jtjs[j*33 + t] = red[0][t] + red[1][t] + red[2][t] + red[3][t];
        return;
    }
    if (bid < 888) {
        // ---- wpack: lbs_weights -> bf16 hi/lo W fragments [v][32] ----
        if (!whi) return;
        int idx = (bid - 24)*256 + t;            // < VPAD*32 exactly
        int v = idx >> 5, j = idx & 31;
        float x = (v < VDIM && j < 24) ? lbs[v*24 + j] : 0.f;
        ushort_t h = bf16_rne(x);
        whi[idx] = h;
        wlo[idx] = bf16_rne(x - bf16_to_f(h));
        return;
    }
    // ---- transpose: posedirs f32 (207 x 20670) -> bf16 (NPAD x KPAD) ----
    int r = bid - 888;
    int nt = (r % 324) * 64;
    int kt = (r / 324) * 32;
    for (int i = t; i < 32*64; i += 256) {
        int kk = i >> 6, nn = i & 63;
        int k = kt + kk, n = nt + nn;
        float v = 0.f;
        if (k < 207 && n < NCOL) v = pd[k*NCOL + n];
        tile[kk][nn] = tob(v);
    }
    __syncthreads();
    {
        // Each thread gathers 8 k-values for one n and writes 16B (was 8x 2B
        // scattered stores). Wave reads tile[kk][lane]: 2B stride, 2 lanes/bank = free.
        int oct = t >> 6, nn = t & 63;
        short8 o;
#pragma unroll
        for (int q = 0; q < 8; q++)
            o[q] = (short)*reinterpret_cast<const ushort_t*>(&tile[oct*8 + q][nn]);
        *reinterpret_cast<short8*>((ushort_t*)pdt + (nt + nn)*KPAD + kt + oct*8) = o;
    }
}

// ---------------- Kernel B: per-batch pose (Rodrigues, chain, A, J_rest, J_posed) ----------------
// Also emits the bf16 hi/lo split of A laid out as MFMA A-fragments
// [b][e(16)][j(32)] so k_gemmlbs phase 3 does guardless short8 loads.
__global__ __launch_bounds__(64) void k_pose(const float* __restrict__ betas,
        const float* __restrict__ pose, const int* __restrict__ parents,
        const float* __restrict__ jtjs, float* __restrict__ out,
        bf16* __restrict__ wspf, ushort_t* __restrict__ ahi,
        ushort_t* __restrict__ alo) {
    int b = blockIdx.x, t = threadIdx.x;
    __shared__ float R[24][9];
    __shared__ float jrest[24][3];
    __shared__ float rel[24][3];
    __shared__ float ch[24][12];
    __shared__ int par[24];
    if (t < 24) {
        par[t] = parents[t];
        float rx = pose[b*72 + t*3 + 0];
        float ry = pose[b*72 + t*3 + 1];
        float rz = pose[b*72 + t*3 + 2];
        float ax = rx + 1e-8f, ay = ry + 1e-8f, az = rz + 1e-8f;
        float angle = sqrtf(ax*ax + ay*ay + az*az);
        float inv = 1.0f / angle;               // axis = original r / angle (ref semantics)
        float kx = rx*inv, ky = ry*inv, kz = rz*inv;
        float s = sinf(angle), c = cosf(angle);
        float t1 = 1.0f - c;
        float q = kx*kx + ky*ky + kz*kz;        // K^2 = kk^T - (k.k) I
        R[t][0] = 1.f + t1*(kx*kx - q);
        R[t][1] = -s*kz + t1*kx*ky;
        R[t][2] =  s*ky + t1*kx*kz;
        R[t][3] =  s*kz + t1*kx*ky;
        R[t][4] = 1.f + t1*(ky*ky - q);
        R[t][5] = -s*kx + t1*ky*kz;
        R[t][6] = -s*ky + t1*kx*kz;
        R[t][7] =  s*kx + t1*ky*kz;
        R[t][8] = 1.f + t1*(kz*kz - q);
    }
    __syncthreads();
    // pose_feature -> scratch (bf16, zero-padded to KPAD)
    for (int i = t; i < KPAD; i += 64) {
        float pf = 0.f;
        if (i < 207) {
            int j = i/9 + 1, e = i - (j-1)*9;
            pf = R[j][e] - ((e == 0 || e == 4 || e == 8) ? 1.f : 0.f);
        }
        wspf[b*KPAD + i] = tob(pf);
    }
    // J_rest = JT + JS . betas   (64 threads -> strided loop over 72)
    for (int i = t; i < 72; i += 64) {
        int j = i/3, k = i - j*3;
        const float* JJ = &jtjs[j*33];
        float s = JJ[k];
#pragma unroll
        for (int l = 0; l < 10; l++) s += JJ[3 + k*10 + l] * betas[b*10 + l];
        jrest[j][k] = s;
        out[OUT_JREST + b*72 + i] = s;
    }
    __syncthreads();
    for (int i = t; i < 72; i += 64) {
        int j = i/3, k = i - j*3;
        rel[j][k] = jrest[j][k] - (j > 0 ? jrest[par[j]][k] : 0.f);
    }
    __syncthreads();
    if (t < 12) {
        int m = t >> 2, n = t & 3;
        ch[0][t] = (n < 3) ? R[0][m*3+n] : rel[0][m];
    }
    __syncthreads();
    for (int i = 1; i < 24; i++) {
        float val = 0.f;
        if (t < 12) {
            int m = t >> 2, n = t & 3;
            int p = par[i];                      // p < i: no overlap with ch[i] write
            if (n < 3)
                val = ch[p][m*4+0]*R[i][n] + ch[p][m*4+1]*R[i][3+n] + ch[p][m*4+2]*R[i][6+n];
            else
                val = ch[p][m*4+0]*rel[i][0] + ch[p][m*4+1]*rel[i][1]
                    + ch[p][m*4+2]*rel[i][2] + ch[p][m*4+3];
        }
        if (t < 12) ch[i][t] = val;
        __syncthreads();
    }
    for (int i = t; i < 72; i += 64) {
        int j = i/3, k = i - j*3;
        out[OUT_JPOSED + b*72 + i] = ch[j][k*4+3];
    }
    // A = chain with translation t - R*jrest (fp32 output; consumers re-read it)
    for (int i = t; i < 384; i += 64) {
        int j = i >> 4, e = i & 15, m = e >> 2, n = e & 3;
        float v;
        if (m < 3) {
            if (n < 3) v = ch[j][m*4+n];
            else v = ch[j][m*4+3] - (ch[j][m*4+0]*jrest[j][0] + ch[j][m*4+1]*jrest[j][1]
                                   + ch[j][m*4+2]*jrest[j][2]);
        } else v = (n == 3) ? 1.f : 0.f;
        out[OUT_A + b*384 + i] = v;
    }
    // A bf16 hi/lo MFMA fragments: [b][e(16)][j(32)], zero-padded.
    if (ahi) {
        for (int i = t; i < 512; i += 64) {
            int e = i >> 5, j = i & 31;
            float v = 0.f;
            if (j < 24 && e < 12) {
                int m = e >> 2, n = e & 3;
                if (n < 3) v = ch[j][m*4+n];
                else v = ch[j][m*4+3] - (ch[j][m*4+0]*jrest[j][0] + ch[j][m*4+1]*jrest[j][1]
                                       + ch[j][m*4+2]*jrest[j][2]);
            }
            ushort_t h = bf16_rne(v);
            ahi[b*512 + i] = h;
            alo[b*512 + i] = bf16_rne(v - bf16_to_f(h));
        }
    }
}

// ---------------- Kernel F (main path): fused pose-GEMM + LBS, all-MFMA ----------------
// R6: occupancy rebuild. R4 (fewer LDS ops) and R5 (in-wave ILP) were both
// neutral at 4 blocks/CU (16 waves, Occupancy 38%) -> the exposed latency is
// structural, hide it with TLP instead: tile = MB=16 batches x 64 vertices,
// LDS 16.6KB, __launch_bounds__(256,8) -> 8 blocks = 32 waves/CU (R4 measured
// 52 VGPR at the BIGGER tile, so the 64-VGPR budget fits). Same math order
// per batch row -> bit-identical outputs.
__global__ __launch_bounds__(256, 8) void k_gemmlbs(const bf16* __restrict__ wspf,
        const bf16* __restrict__ wspdt, const float* __restrict__ betas,
        const float* __restrict__ sd, const float* __restrict__ vt,
        const ushort_t* __restrict__ whi, const ushort_t* __restrict__ wlo,
        const ushort_t* __restrict__ ahi, const ushort_t* __restrict__ alo,
        float* __restrict__ out) {
    __shared__ float dtile[MB][260];
    const ushort_t* pf  = (const ushort_t*)wspf;
    const ushort_t* pdt = (const ushort_t*)wspdt;
    int tid  = threadIdx.x;
    int lane = tid & 63, wave = tid >> 6;
    int l15 = lane & 15, quad = lane >> 4;
    int m0 = blockIdx.y * MB;          // batch base
    int v0 = blockIdx.x * 64;          // vertex base
    int cb = wave * 48;                // wave's col base within tile
    int colb = v0*3 + cb;              // global col base (max 20735 < NPAD)
    int wv = __builtin_amdgcn_readfirstlane(wave);   // provably uniform batch group

    // ---- Phase 1: pose-delta GEMM (bf16 K=224), 16 batch rows ----
    {
        float4v acc[3] = {};
        for (int c = 0; c < 7; c++) {
            short8 a = *reinterpret_cast<const short8*>(pf + (m0 + l15)*KPAD + c*32 + quad*8);
            short8 bb[3];
#pragma unroll
            for (int nf = 0; nf < 3; nf++)
                bb[nf] = *reinterpret_cast<const short8*>(pdt + (colb + nf*16 + l15)*KPAD + c*32 + quad*8);
#pragma unroll
            for (int nf = 0; nf < 3; nf++)
                acc[nf] = __builtin_amdgcn_mfma_f32_16x16x32_bf16(a, bb[nf], acc[nf], 0, 0, 0);
        }
#pragma unroll
        for (int nf = 0; nf < 3; nf++) {
            int c0 = cb + nf*16 + l15;           // col in [0,192)
            int vv = c0 / 3, rr = c0 - vv*3;     // vertex-in-tile, component
            int ad = vv*4 + rr;                  // padded float4 slot
#pragma unroll
            for (int r = 0; r < 4; r++)
                dtile[quad*4 + r][ad] = acc[nf][r];
        }
    }
    __syncthreads();

    // ---- Phase 2: vs, vp in-place (b128 RMW), vsh (lane = vertex, 4 batches/wave) ----
    int v = v0 + lane;
    float* vsh = out + OUT_VSHAPED;
    if (v < VDIM) {
        float vtv[3];
#pragma unroll
        for (int m = 0; m < 3; m++) vtv[m] = vt[v*3 + m];
        float sdv[30];
#pragma unroll
        for (int i = 0; i < 30; i++) sdv[i] = sd[v*30 + i];
#pragma unroll 2
        for (int bb2 = 0; bb2 < 4; bb2++) {
            int b  = m0 + wv*4 + bb2;                // scalar
            int bl = wv*4 + bb2;
            float vs[3];
#pragma unroll
            for (int m = 0; m < 3; m++) {
                float s = vtv[m];
#pragma unroll
                for (int l = 0; l < 10; l++) s += betas[b*10 + l] * sdv[m*10 + l];
                vs[m] = s;
            }
            float4v* slot = reinterpret_cast<float4v*>(&dtile[bl][lane*4]);
            float4v d = *slot;
            float4v vp;
            vp[0] = vs[0] + d[0]; vp[1] = vs[1] + d[1];
            vp[2] = vs[2] + d[2]; vp[3] = 0.f;
            *slot = vp;
            int base = b*NCOL + v*3;
#pragma unroll
            for (int n = 0; n < 3; n++) vsh[base + n] = vs[n];
        }
    }
    // NOTE: no barrier -- dtile rows [wv*4, wv*4+4) are wave-private from here.

    // ---- Phase 3: T via 3-split MFMA (precomputed A-frags) + apply ----
    short8 bhi[4], blo[4];
#pragma unroll
    for (int nf = 0; nf < 4; nf++) {
        int vv = v0 + nf*16 + l15;                   // < VPAD, padded
        bhi[nf] = *reinterpret_cast<const short8*>(whi + vv*32 + quad*8);
        blo[nf] = *reinterpret_cast<const short8*>(wlo + vv*32 + quad*8);
    }
    const ushort_t* ah = ahi + (size_t)(m0 + wv*4)*512 + l15*32 + quad*8;
    const ushort_t* al = alo + (size_t)(m0 + wv*4)*512 + l15*32 + quad*8;
#pragma unroll 1
    for (int bb2 = 0; bb2 < 4; bb2++) {
        int b  = m0 + wv*4 + bb2;
        int bl = wv*4 + bb2;
        short8 a_hi = *reinterpret_cast<const short8*>(ah + (size_t)bb2*512);
        short8 a_lo = *reinterpret_cast<const short8*>(al + (size_t)bb2*512);
#pragma unroll
        for (int nf = 0; nf < 4; nf++) {
            float4v acc = {};
            acc = __builtin_amdgcn_mfma_f32_16x16x32_bf16(a_hi, bhi[nf], acc, 0, 0, 0);
            acc = __builtin_amdgcn_mfma_f32_16x16x32_bf16(a_lo, bhi[nf], acc, 0, 0, 0);
            acc = __builtin_amdgcn_mfma_f32_16x16x32_bf16(a_hi, blo[nf], acc, 0, 0, 0);
            int vl = nf*16 + l15;
            float4v vp = *reinterpret_cast<const float4v*>(&dtile[bl][vl*4]);
            if (quad < 3 && v0 + vl < VDIM) {
                // acc[r]: row e = quad*4+r -> T[m=quad][n=r]
                float o = acc[3] + acc[0]*vp[0] + acc[1]*vp[1] + acc[2]*vp[2];
                out[(size_t)b*NCOL + (size_t)(v0 + vl)*3 + quad] = o;
            }
        }
    }
}

// ---------------- Fallback kernels (ws too small): R1 pipeline ----------------
__global__ __launch_bounds__(256) void k_posegemm(const bf16* __restrict__ wspf,
        const bf16* __restrict__ wspdt, float* __restrict__ dout) {
    const ushort_t* pf  = (const ushort_t*)wspf;
    const ushort_t* pdt = (const ushort_t*)wspdt;
    int lane = threadIdx.x & 63;
    int wave = threadIdx.x >> 6;
    int l15 = lane & 15, quad = lane >> 4;
    int m0 = blockIdx.y * 32;
    int n0 = blockIdx.x * 256 + wave * 64;
    float4v acc[2][4] = {};
    for (int c = 0; c < 7; c++) {
        short8 a[2], bb[4];
#pragma unroll
        for (int mf = 0; mf < 2; mf++)
            a[mf] = *reinterpret_cast<const short8*>(pf + (m0 + mf*16 + l15)*KPAD + c*32 + quad*8);
#pragma unroll
        for (int nf = 0; nf < 4; nf++)
            bb[nf] = *reinterpret_cast<const short8*>(pdt + (n0 + nf*16 + l15)*KPAD + c*32 + quad*8);
#pragma unroll
        for (int mf = 0; mf < 2; mf++)
#pragma unroll
            for (int nf = 0; nf < 4; nf++)
                acc[mf][nf] = __builtin_amdgcn_mfma_f32_16x16x32_bf16(a[mf], bb[nf], acc[mf][nf], 0, 0, 0);
    }
#pragma unroll
    for (int mf = 0; mf < 2; mf++)
#pragma unroll
        for (int nf = 0; nf < 4; nf++) {
            int col = n0 + nf*16 + l15;
            if (col < NCOL) {
#pragma unroll
                for (int r = 0; r < 4; r++) {
                    int row = m0 + mf*16 + quad*4 + r;
                    dout[row*NCOL + col] = acc[mf][nf][r];
                }
            }
        }
}

__global__ __launch_bounds__(256) void k_lbs(const float* __restrict__ betas,
        const float* __restrict__ sd, const float* __restrict__ vt,
        const float* __restrict__ lbs, const float* __restrict__ Amat,
        float* __restrict__ out) {
    int tid = threadIdx.x;
    int v = blockIdx.x*256 + tid;
    if (v >= VDIM) return;
    int b0 = blockIdx.y * NB;
    float w[24];
    {
        const float4v* W4 = reinterpret_cast<const float4v*>(lbs + v*24);
#pragma unroll
        for (int q = 0; q < 6; q++) {
            float4v x = W4[q];
#pragma unroll
            for (int e = 0; e < 4; e++) w[q*4+e] = x[e];
        }
    }
    float vtv[3];
#pragma unroll
    for (int m = 0; m < 3; m++) vtv[m] = vt[v*3 + m];
    float sdv[30];
#pragma unroll
    for (int i = 0; i < 30; i++) sdv[i] = sd[v*30 + i];
    float* vsh = out + OUT_VSHAPED;
#pragma unroll 1
    for (int bb = 0; bb < NB; bb++) {
        int b = b0 + bb;
        const float* __restrict__ Ab = Amat + (size_t)b*384;
        float T[12];
#pragma unroll
        for (int e = 0; e < 12; e++) T[e] = 0.f;
#pragma unroll
        for (int j = 0; j < 24; j++) {
#pragma unroll
            for (int e = 0; e < 12; e++)
                T[e] = fmaf(w[j], Ab[j*16 + e], T[e]);
        }
        float vs[3];
#pragma unroll
        for (int m = 0; m < 3; m++) {
            float s = vtv[m];
#pragma unroll
            for (int l = 0; l < 10; l++) s += betas[b*10 + l] * sdv[m*10 + l];
            vs[m] = s;
        }
        int base = b*NCOL + v*3;
        float vp0 = vs[0] + vsh[base + 0];
        float vp1 = vs[1] + vsh[base + 1];
        float vp2 = vs[2] + vsh[base + 2];
#pragma unroll
        for (int m = 0; m < 3; m++) {
            float o = T[m*4+3] + T[m*4]*vp0 + T[m*4+1]*vp1 + T[m*4+2]*vp2;
            out[base + m] = o;
            vsh[base + m] = vs[m];
        }
    }
}

extern "C" void kernel_launch(void* const* d_in, const int* in_sizes, int n_in,
                              void* d_out, int out_size, void* d_ws, size_t ws_size,
                              hipStream_t stream) {
    const float *betas = nullptr, *pose = nullptr, *vt = nullptr, *sd = nullptr,
                *pd = nullptr, *jreg = nullptr, *lbs = nullptr;
    const int* parents = nullptr;
    for (int i = 0; i < n_in; i++) {
        switch (in_sizes[i]) {
            case 10240:   betas = (const float*)d_in[i]; break;      // (1024,10)
            case 73728:   pose  = (const float*)d_in[i]; break;      // (1024,72)
            case 20670:   vt    = (const float*)d_in[i]; break;      // (1,6890,3)
            case 206700:  sd    = (const float*)d_in[i]; break;      // (6890,3,10)
            case 4278690: pd    = (const float*)d_in[i]; break;      // (207,20670)
            case 24:      parents = (const int*)d_in[i]; break;      // (24,)
            case 165360:                                             // (24,6890)/(6890,24)
                if (!jreg) jreg = (const float*)d_in[i];
                else       lbs  = (const float*)d_in[i];
                break;
            default: break;
        }
    }
    float* out = (float*)d_out;
    if (d_ws && ws_size >= (size_t)WS_NEED) {
        // Main path: scratch in workspace; fused all-MFMA GEMM+LBS.
        bf16*     ws_pdt  = (bf16*)((char*)d_ws + WSB_PDT);
        bf16*     ws_pf   = (bf16*)((char*)d_ws + WSB_PF);
        float*    ws_jtjs = (float*)((char*)d_ws + WSB_JTJS);
        ushort_t* ws_whi  = (ushort_t*)((char*)d_ws + WSB_WHI);
        ushort_t* ws_wlo  = (ushort_t*)((char*)d_ws + WSB_WLO);
        ushort_t* ws_ahi  = (ushort_t*)((char*)d_ws + WSB_AHI);
        ushort_t* ws_alo  = (ushort_t*)((char*)d_ws + WSB_ALO);
        k_prep2<<<3156, 256, 0, stream>>>(jreg, vt, sd, lbs, pd, ws_jtjs,
                                          ws_whi, ws_wlo, ws_pdt);
        k_pose<<<BDIM, 64, 0, stream>>>(betas, pose, parents, ws_jtjs, out, ws_pf,
                                        ws_ahi, ws_alo);
        k_gemmlbs<<<dim3(108, BDIM/MB), 256, 0, stream>>>(ws_pf, ws_pdt, betas, sd, vt,
                                                     ws_whi, ws_wlo, ws_ahi, ws_alo, out);
    } else {
        // Fallback (R1 pipeline): scratch inside the verts region of d_out.
        bf16*  ws_pdt  = (bf16*)(out + SCRF_PDT);
        bf16*  ws_pf   = (bf16*)(out + SCRF_PF);
        float* ws_jtjs = out + SCRF_JTJS;
        k_prep2<<<3156, 256, 0, stream>>>(jreg, vt, sd, lbs, pd, ws_jtjs,
                                          nullptr, nullptr, ws_pdt);
        k_pose<<<BDIM, 64, 0, stream>>>(betas, pose, parents, ws_jtjs, out, ws_pf,
                                        nullptr, nullptr);
        k_posegemm<<<dim3(81, 32), 256, 0, stream>>>(ws_pf, ws_pdt, out + OUT_VSHAPED);
        k_lbs<<<dim3(27, BDIM/NB), 256, 0, stream>>>(betas, sd, vt, lbs, out + OUT_A, out);
    }
}

// Round 8
// 325.376 us; speedup vs baseline: 1.0033x; 1.0033x over previous
//
#include <hip/hip_runtime.h>
#include <hip/hip_bf16.h>

#define BDIM 1024
#define VDIM 6890
#define NJ   24
#define NCOL (VDIM*3)   // 20670
#define KPAD 224        // 207 padded to 7*32
#define NPAD 20736      // 108*192 = 81*256 columns, zero-padded for guardless loads
#define NB   8          // batches per k_lbs block (fallback path)
#define VPAD 6912       // 108*64 vertices, zero-padded for W fragments
#define MB   16         // batches per k_gemmlbs block

// fp32-element offsets into d_out (float*):
#define OUT_VERTS   0
#define OUT_JPOSED  21166080
#define OUT_JREST   21239808
#define OUT_A       21313536
#define OUT_VSHAPED 21706752

// Fallback-path scratch inside the verts region of d_out (dead before k_lbs
// writes verts). Offsets in fp32 elements; pdt/pf are bf16 arrays.
#define SCRF_PDT    0          // bf16 NPAD*KPAD
#define SCRF_PF     2322432    // bf16 1024*224
#define SCRF_JTJS   2437120    // 792 f32

// Workspace layout (main fused path), byte offsets:
#define WSB_PDT   0u
#define WSB_PF    9289728u                    // NPAD*KPAD*2
#define WSB_JTJS  9748480u                    // + 1024*KPAD*2
#define WSB_WHI   9752064u                    // jtjs 3168 B, aligned up
#define WSB_WLO   10194432u                   // + VPAD*32*2
#define WSB_AHI   10636800u                   // + VPAD*32*2
#define WSB_ALO   11685376u                   // + 1024*512*2
#define WS_NEED   12733952u                   // + 1024*512*2

typedef __hip_bfloat16 bf16;
typedef unsigned short ushort_t;
typedef __attribute__((ext_vector_type(8))) short  short8;
typedef __attribute__((ext_vector_type(4))) float  float4v;

__device__ __forceinline__ bf16  tob(float x) { return __float2bfloat16(x); }

// RNE float->bf16 bit helpers (self-consistent hi/lo split; finite inputs only)
__device__ __forceinline__ ushort_t bf16_rne(float x) {
    unsigned u = __builtin_bit_cast(unsigned, x);
    unsigned r = (u + 0x7FFFu + ((u >> 16) & 1u)) >> 16;
    return (ushort_t)r;
}
__device__ __forceinline__ float bf16_to_f(ushort_t h) {
    unsigned u = ((unsigned)h) << 16;
    return __builtin_bit_cast(float, u);
}

// ---------------- Kernel P2: jtjs + wpack + posedirs-transpose in ONE launch ----------------
// blocks [0,24): jtjs. [24,888): wpack (skipped if whi==null). [888,3156): transpose.
__global__ __launch_bounds__(256) void k_prep2(const float* __restrict__ jreg,
        const float* __restrict__ vt, const float* __restrict__ sd,
        const float* __restrict__ lbs, const float* __restrict__ pd,
        float* __restrict__ jtjs, ushort_t* __restrict__ whi,
        ushort_t* __restrict__ wlo, bf16* __restrict__ pdt) {
    __shared__ float red[4][33];
    __shared__ bf16 tile[32][65];
    int bid = blockIdx.x;
    int t = threadIdx.x;
    if (bid < 24) {
        // ---- jtjs: [JT|JS](24 x 33) = jreg(24 x V) @ [vt|sd](V x 33) ----
        int j = bid;
        float acc[33];
#pragma unroll
        for (int i = 0; i < 33; i++) acc[i] = 0.f;
        for (int v = t; v < VDIM; v += 256) {
            float r = jreg[j*VDIM + v];
#pragma unroll
            for (int m = 0; m < 3; m++) {
                acc[m] += r * vt[v*3+m];
#pragma unroll
                for (int l = 0; l < 10; l++)
                    acc[3 + m*10 + l] += r * sd[(v*3+m)*10 + l];
            }
        }
        int lane = t & 63, wid = t >> 6;
#pragma unroll
        for (int i = 0; i < 33; i++) {
            float x = acc[i];
            for (int off = 32; off > 0; off >>= 1) x += __shfl_down(x, off);
            if (lane == 0) red[wid][i] = x;
        }
        __syncthreads();
        if (t < 33)
            jtjs[j*33 + t] = red[0][t] + red[1][t] + red[2][t] + red[3][t];
        return;
    }
    if (bid < 888) {
        // ---- wpack: lbs_weights -> bf16 hi/lo W fragments [v][32] ----
        if (!whi) return;
        int idx = (bid - 24)*256 + t;            // < VPAD*32 exactly
        int v = idx >> 5, j = idx & 31;
        float x = (v < VDIM && j < 24) ? lbs[v*24 + j] : 0.f;
        ushort_t h = bf16_rne(x);
        whi[idx] = h;
        wlo[idx] = bf16_rne(x - bf16_to_f(h));
        return;
    }
    // ---- transpose: posedirs f32 (207 x 20670) -> bf16 (NPAD x KPAD) ----
    int r = bid - 888;
    int nt = (r % 324) * 64;
    int kt = (r / 324) * 32;
    for (int i = t; i < 32*64; i += 256) {
        int kk = i >> 6, nn = i & 63;
        int k = kt + kk, n = nt + nn;
        float v = 0.f;
        if (k < 207 && n < NCOL) v = pd[k*NCOL + n];
        tile[kk][nn] = tob(v);
    }
    __syncthreads();
    {
        int oct = t >> 6, nn = t & 63;
        short8 o;
#pragma unroll
        for (int q = 0; q < 8; q++)
            o[q] = (short)*reinterpret_cast<const ushort_t*>(&tile[oct*8 + q][nn]);
        *reinterpret_cast<short8*>((ushort_t*)pdt + (nt + nn)*KPAD + kt + oct*8) = o;
    }
}

// ---------------- Kernel B: per-batch pose (Rodrigues, chain, A, J_rest, J_posed) ----------------
__global__ __launch_bounds__(64) void k_pose(const float* __restrict__ betas,
        const float* __restrict__ pose, const int* __restrict__ parents,
        const float* __restrict__ jtjs, float* __restrict__ out,
        bf16* __restrict__ wspf, ushort_t* __restrict__ ahi,
        ushort_t* __restrict__ alo) {
    int b = blockIdx.x, t = threadIdx.x;
    __shared__ float R[24][9];
    __shared__ float jrest[24][3];
    __shared__ float rel[24][3];
    __shared__ float ch[24][12];
    __shared__ int par[24];
    if (t < 24) {
        par[t] = parents[t];
        float rx = pose[b*72 + t*3 + 0];
        float ry = pose[b*72 + t*3 + 1];
        float rz = pose[b*72 + t*3 + 2];
        float ax = rx + 1e-8f, ay = ry + 1e-8f, az = rz + 1e-8f;
        float angle = sqrtf(ax*ax + ay*ay + az*az);
        float inv = 1.0f / angle;               // axis = original r / angle (ref semantics)
        float kx = rx*inv, ky = ry*inv, kz = rz*inv;
        float s = sinf(angle), c = cosf(angle);
        float t1 = 1.0f - c;
        float q = kx*kx + ky*ky + kz*kz;        // K^2 = kk^T - (k.k) I
        R[t][0] = 1.f + t1*(kx*kx - q);
        R[t][1] = -s*kz + t1*kx*ky;
        R[t][2] =  s*ky + t1*kx*kz;
        R[t][3] =  s*kz + t1*kx*ky;
        R[t][4] = 1.f + t1*(ky*ky - q);
        R[t][5] = -s*kx + t1*ky*kz;
        R[t][6] = -s*ky + t1*kx*kz;
        R[t][7] =  s*kx + t1*ky*kz;
        R[t][8] = 1.f + t1*(kz*kz - q);
    }
    __syncthreads();
    // pose_feature -> scratch (bf16, zero-padded to KPAD)
    for (int i = t; i < KPAD; i += 64) {
        float pf = 0.f;
        if (i < 207) {
            int j = i/9 + 1, e = i - (j-1)*9;
            pf = R[j][e] - ((e == 0 || e == 4 || e == 8) ? 1.f : 0.f);
        }
        wspf[b*KPAD + i] = tob(pf);
    }
    // J_rest = JT + JS . betas
    for (int i = t; i < 72; i += 64) {
        int j = i/3, k = i - j*3;
        const float* JJ = &jtjs[j*33];
        float s = JJ[k];
#pragma unroll
        for (int l = 0; l < 10; l++) s += JJ[3 + k*10 + l] * betas[b*10 + l];
        jrest[j][k] = s;
        out[OUT_JREST + b*72 + i] = s;
    }
    __syncthreads();
    for (int i = t; i < 72; i += 64) {
        int j = i/3, k = i - j*3;
        rel[j][k] = jrest[j][k] - (j > 0 ? jrest[par[j]][k] : 0.f);
    }
    __syncthreads();
    if (t < 12) {
        int m = t >> 2, n = t & 3;
        ch[0][t] = (n < 3) ? R[0][m*3+n] : rel[0][m];
    }
    __syncthreads();
    for (int i = 1; i < 24; i++) {
        float val = 0.f;
        if (t < 12) {
            int m = t >> 2, n = t & 3;
            int p = par[i];                      // p < i: no overlap with ch[i] write
            if (n < 3)
                val = ch[p][m*4+0]*R[i][n] + ch[p][m*4+1]*R[i][3+n] + ch[p][m*4+2]*R[i][6+n];
            else
                val = ch[p][m*4+0]*rel[i][0] + ch[p][m*4+1]*rel[i][1]
                    + ch[p][m*4+2]*rel[i][2] + ch[p][m*4+3];
        }
        if (t < 12) ch[i][t] = val;
        __syncthreads();
    }
    for (int i = t; i < 72; i += 64) {
        int j = i/3, k = i - j*3;
        out[OUT_JPOSED + b*72 + i] = ch[j][k*4+3];
    }
    // A = chain with translation t - R*jrest (fp32 output; consumers re-read it)
    for (int i = t; i < 384; i += 64) {
        int j = i >> 4, e = i & 15, m = e >> 2, n = e & 3;
        float v;
        if (m < 3) {
            if (n < 3) v = ch[j][m*4+n];
            else v = ch[j][m*4+3] - (ch[j][m*4+0]*jrest[j][0] + ch[j][m*4+1]*jrest[j][1]
                                   + ch[j][m*4+2]*jrest[j][2]);
        } else v = (n == 3) ? 1.f : 0.f;
        out[OUT_A + b*384 + i] = v;
    }
    // A bf16 hi/lo MFMA fragments: [b][e(16)][j(32)], zero-padded.
    if (ahi) {
        for (int i = t; i < 512; i += 64) {
            int e = i >> 5, j = i & 31;
            float v = 0.f;
            if (j < 24 && e < 12) {
                int m = e >> 2, n = e & 3;
                if (n < 3) v = ch[j][m*4+n];
                else v = ch[j][m*4+3] - (ch[j][m*4+0]*jrest[j][0] + ch[j][m*4+1]*jrest[j][1]
                                       + ch[j][m*4+2]*jrest[j][2]);
            }
            ushort_t h = bf16_rne(v);
            ahi[b*512 + i] = h;
            alo[b*512 + i] = bf16_rne(v - bf16_to_f(h));
        }
    }
}

// ---------------- Kernel F (main path): fused pose-GEMM + LBS, all-MFMA ----------------
// R7: store-path fix. R6 counters showed FETCH=121MB vs ~14MB compulsory and
// WRITE=198 vs 169: phase-3's 4B-stride-12 verts stores caused write-allocate
// RMW on the whole 84.7MB verts region (+ re-writeback). Fix: park o in the
// spare word of each vertex slot in dtile (quad q -> bank set {q,q+4,..},
// 2 lanes/bank = free; in-wave lockstep makes the in-place overwrite safe),
// then phase 4 streams verts out contiguously (lane=vertex, 768B/wave full
// lines, same pattern as the vsh writes that already measure clean).
__global__ __launch_bounds__(256, 8) void k_gemmlbs(const bf16* __restrict__ wspf,
        const bf16* __restrict__ wspdt, const float* __restrict__ betas,
        const float* __restrict__ sd, const float* __restrict__ vt,
        const ushort_t* __restrict__ whi, const ushort_t* __restrict__ wlo,
        const ushort_t* __restrict__ ahi, const ushort_t* __restrict__ alo,
        float* __restrict__ out) {
    __shared__ float dtile[MB][260];
    const ushort_t* pf  = (const ushort_t*)wspf;
    const ushort_t* pdt = (const ushort_t*)wspdt;
    int tid  = threadIdx.x;
    int lane = tid & 63, wave = tid >> 6;
    int l15 = lane & 15, quad = lane >> 4;
    int m0 = blockIdx.y * MB;          // batch base
    int v0 = blockIdx.x * 64;          // vertex base
    int cb = wave * 48;                // wave's col base within tile
    int colb = v0*3 + cb;              // global col base (max 20735 < NPAD)
    int wv = __builtin_amdgcn_readfirstlane(wave);   // provably uniform batch group

    // ---- Phase 1: pose-delta GEMM (bf16 K=224), 16 batch rows ----
    {
        float4v acc[3] = {};
        for (int c = 0; c < 7; c++) {
            short8 a = *reinterpret_cast<const short8*>(pf + (m0 + l15)*KPAD + c*32 + quad*8);
            short8 bb[3];
#pragma unroll
            for (int nf = 0; nf < 3; nf++)
                bb[nf] = *reinterpret_cast<const short8*>(pdt + (colb + nf*16 + l15)*KPAD + c*32 + quad*8);
#pragma unroll
            for (int nf = 0; nf < 3; nf++)
                acc[nf] = __builtin_amdgcn_mfma_f32_16x16x32_bf16(a, bb[nf], acc[nf], 0, 0, 0);
        }
#pragma unroll
        for (int nf = 0; nf < 3; nf++) {
            int c0 = cb + nf*16 + l15;           // col in [0,192)
            int vv = c0 / 3, rr = c0 - vv*3;     // vertex-in-tile, component
            int ad = vv*4 + rr;                  // padded float4 slot
#pragma unroll
            for (int r = 0; r < 4; r++)
                dtile[quad*4 + r][ad] = acc[nf][r];
        }
    }
    __syncthreads();

    // ---- Phase 2: vs, vp in-place (b128 RMW), vsh (lane = vertex, 4 batches/wave) ----
    int v = v0 + lane;
    float* vsh = out + OUT_VSHAPED;
    if (v < VDIM) {
        float vtv[3];
#pragma unroll
        for (int m = 0; m < 3; m++) vtv[m] = vt[v*3 + m];
        float sdv[30];
#pragma unroll
        for (int i = 0; i < 30; i++) sdv[i] = sd[v*30 + i];
#pragma unroll 2
        for (int bb2 = 0; bb2 < 4; bb2++) {
            int b  = m0 + wv*4 + bb2;                // scalar
            int bl = wv*4 + bb2;
            float vs[3];
#pragma unroll
            for (int m = 0; m < 3; m++) {
                float s = vtv[m];
#pragma unroll
                for (int l = 0; l < 10; l++) s += betas[b*10 + l] * sdv[m*10 + l];
                vs[m] = s;
            }
            float4v* slot = reinterpret_cast<float4v*>(&dtile[bl][lane*4]);
            float4v d = *slot;
            float4v vp;
            vp[0] = vs[0] + d[0]; vp[1] = vs[1] + d[1];
            vp[2] = vs[2] + d[2]; vp[3] = 0.f;
            *slot = vp;
            int base = b*NCOL + v*3;
#pragma unroll
            for (int n = 0; n < 3; n++) vsh[base + n] = vs[n];
        }
    }
    // NOTE: no barrier -- dtile rows [wv*4, wv*4+4) are wave-private from here.

    // ---- Phase 3: T via 3-split MFMA (precomputed A-frags); o -> LDS slot ----
    short8 bhi[4], blo[4];
#pragma unroll
    for (int nf = 0; nf < 4; nf++) {
        int vv = v0 + nf*16 + l15;                   // < VPAD, padded
        bhi[nf] = *reinterpret_cast<const short8*>(whi + vv*32 + quad*8);
        blo[nf] = *reinterpret_cast<const short8*>(wlo + vv*32 + quad*8);
    }
    const ushort_t* ah = ahi + (size_t)(m0 + wv*4)*512 + l15*32 + quad*8;
    const ushort_t* al = alo + (size_t)(m0 + wv*4)*512 + l15*32 + quad*8;
#pragma unroll 1
    for (int bb2 = 0; bb2 < 4; bb2++) {
        int bl = wv*4 + bb2;
        short8 a_hi = *reinterpret_cast<const short8*>(ah + (size_t)bb2*512);
        short8 a_lo = *reinterpret_cast<const short8*>(al + (size_t)bb2*512);
#pragma unroll
        for (int nf = 0; nf < 4; nf++) {
            float4v acc = {};
            acc = __builtin_amdgcn_mfma_f32_16x16x32_bf16(a_hi, bhi[nf], acc, 0, 0, 0);
            acc = __builtin_amdgcn_mfma_f32_16x16x32_bf16(a_lo, bhi[nf], acc, 0, 0, 0);
            acc = __builtin_amdgcn_mfma_f32_16x16x32_bf16(a_hi, blo[nf], acc, 0, 0, 0);
            int vl = nf*16 + l15;
            // lockstep: all lanes' vp reads issue before any o write
            float4v vp = *reinterpret_cast<const float4v*>(&dtile[bl][vl*4]);
            if (quad < 3) {
                // acc[r]: row e = quad*4+r -> T[m=quad][n=r]
                float o = acc[3] + acc[0]*vp[0] + acc[1]*vp[1] + acc[2]*vp[2];
                dtile[bl][vl*4 + quad] = o;          // park in spare-word slot
            }
        }
    }

    // ---- Phase 4: contiguous verts write-out (lane = vertex, full lines) ----
    if (v < VDIM) {
#pragma unroll
        for (int bb2 = 0; bb2 < 4; bb2++) {
            int b  = m0 + wv*4 + bb2;
            int bl = wv*4 + bb2;
            float4v o = *reinterpret_cast<const float4v*>(&dtile[bl][lane*4]);
            int base = b*NCOL + v*3;
            out[base + 0] = o[0];
            out[base + 1] = o[1];
            out[base + 2] = o[2];
        }
    }
}

// ---------------- Fallback kernels (ws too small): R1 pipeline ----------------
__global__ __launch_bounds__(256) void k_posegemm(const bf16* __restrict__ wspf,
        const bf16* __restrict__ wspdt, float* __restrict__ dout) {
    const ushort_t* pf  = (const ushort_t*)wspf;
    const ushort_t* pdt = (const ushort_t*)wspdt;
    int lane = threadIdx.x & 63;
    int wave = threadIdx.x >> 6;
    int l15 = lane & 15, quad = lane >> 4;
    int m0 = blockIdx.y * 32;
    int n0 = blockIdx.x * 256 + wave * 64;
    float4v acc[2][4] = {};
    for (int c = 0; c < 7; c++) {
        short8 a[2], bb[4];
#pragma unroll
        for (int mf = 0; mf < 2; mf++)
            a[mf] = *reinterpret_cast<const short8*>(pf + (m0 + mf*16 + l15)*KPAD + c*32 + quad*8);
#pragma unroll
        for (int nf = 0; nf < 4; nf++)
            bb[nf] = *reinterpret_cast<const short8*>(pdt + (n0 + nf*16 + l15)*KPAD + c*32 + quad*8);
#pragma unroll
        for (int mf = 0; mf < 2; mf++)
#pragma unroll
            for (int nf = 0; nf < 4; nf++)
                acc[mf][nf] = __builtin_amdgcn_mfma_f32_16x16x32_bf16(a[mf], bb[nf], acc[mf][nf], 0, 0, 0);
    }
#pragma unroll
    for (int mf = 0; mf < 2; mf++)
#pragma unroll
        for (int nf = 0; nf < 4; nf++) {
            int col = n0 + nf*16 + l15;
            if (col < NCOL) {
#pragma unroll
                for (int r = 0; r < 4; r++) {
                    int row = m0 + mf*16 + quad*4 + r;
                    dout[row*NCOL + col] = acc[mf][nf][r];
                }
            }
        }
}

__global__ __launch_bounds__(256) void k_lbs(const float* __restrict__ betas,
        const float* __restrict__ sd, const float* __restrict__ vt,
        const float* __restrict__ lbs, const float* __restrict__ Amat,
        float* __restrict__ out) {
    int tid = threadIdx.x;
    int v = blockIdx.x*256 + tid;
    if (v >= VDIM) return;
    int b0 = blockIdx.y * NB;
    float w[24];
    {
        const float4v* W4 = reinterpret_cast<const float4v*>(lbs + v*24);
#pragma unroll
        for (int q = 0; q < 6; q++) {
            float4v x = W4[q];
#pragma unroll
            for (int e = 0; e < 4; e++) w[q*4+e] = x[e];
        }
    }
    float vtv[3];
#pragma unroll
    for (int m = 0; m < 3; m++) vtv[m] = vt[v*3 + m];
    float sdv[30];
#pragma unroll
    for (int i = 0; i < 30; i++) sdv[i] = sd[v*30 + i];
    float* vsh = out + OUT_VSHAPED;
#pragma unroll 1
    for (int bb = 0; bb < NB; bb++) {
        int b = b0 + bb;
        const float* __restrict__ Ab = Amat + (size_t)b*384;
        float T[12];
#pragma unroll
        for (int e = 0; e < 12; e++) T[e] = 0.f;
#pragma unroll
        for (int j = 0; j < 24; j++) {
#pragma unroll
            for (int e = 0; e < 12; e++)
                T[e] = fmaf(w[j], Ab[j*16 + e], T[e]);
        }
        float vs[3];
#pragma unroll
        for (int m = 0; m < 3; m++) {
            float s = vtv[m];
#pragma unroll
            for (int l = 0; l < 10; l++) s += betas[b*10 + l] * sdv[m*10 + l];
            vs[m] = s;
        }
        int base = b*NCOL + v*3;
        float vp0 = vs[0] + vsh[base + 0];
        float vp1 = vs[1] + vsh[base + 1];
        float vp2 = vs[2] + vsh[base + 2];
#pragma unroll
        for (int m = 0; m < 3; m++) {
            float o = T[m*4+3] + T[m*4]*vp0 + T[m*4+1]*vp1 + T[m*4+2]*vp2;
            out[base + m] = o;
            vsh[base + m] = vs[m];
        }
    }
}

extern "C" void kernel_launch(void* const* d_in, const int* in_sizes, int n_in,
                              void* d_out, int out_size, void* d_ws, size_t ws_size,
                              hipStream_t stream) {
    const float *betas = nullptr, *pose = nullptr, *vt = nullptr, *sd = nullptr,
                *pd = nullptr, *jreg = nullptr, *lbs = nullptr;
    const int* parents = nullptr;
    for (int i = 0; i < n_in; i++) {
        switch (in_sizes[i]) {
            case 10240:   betas = (const float*)d_in[i]; break;      // (1024,10)
            case 73728:   pose  = (const float*)d_in[i]; break;      // (1024,72)
            case 20670:   vt    = (const float*)d_in[i]; break;      // (1,6890,3)
            case 206700:  sd    = (const float*)d_in[i]; break;      // (6890,3,10)
            case 4278690: pd    = (const float*)d_in[i]; break;      // (207,20670)
            case 24:      parents = (const int*)d_in[i]; break;      // (24,)
            case 165360:                                             // (24,6890)/(6890,24)
                if (!jreg) jreg = (const float*)d_in[i];
                else       lbs  = (const float*)d_in[i];
                break;
            default: break;
        }
    }
    float* out = (float*)d_out;
    if (d_ws && ws_size >= (size_t)WS_NEED) {
        // Main path: scratch in workspace; fused all-MFMA GEMM+LBS.
        bf16*     ws_pdt  = (bf16*)((char*)d_ws + WSB_PDT);
        bf16*     ws_pf   = (bf16*)((char*)d_ws + WSB_PF);
        float*    ws_jtjs = (float*)((char*)d_ws + WSB_JTJS);
        ushort_t* ws_whi  = (ushort_t*)((char*)d_ws + WSB_WHI);
        ushort_t* ws_wlo  = (ushort_t*)((char*)d_ws + WSB_WLO);
        ushort_t* ws_ahi  = (ushort_t*)((char*)d_ws + WSB_AHI);
        ushort_t* ws_alo  = (ushort_t*)((char*)d_ws + WSB_ALO);
        k_prep2<<<3156, 256, 0, stream>>>(jreg, vt, sd, lbs, pd, ws_jtjs,
                                          ws_whi, ws_wlo, ws_pdt);
        k_pose<<<BDIM, 64, 0, stream>>>(betas, pose, parents, ws_jtjs, out, ws_pf,
                                        ws_ahi, ws_alo);
        k_gemmlbs<<<dim3(108, BDIM/MB), 256, 0, stream>>>(ws_pf, ws_pdt, betas, sd, vt,
                                                     ws_whi, ws_wlo, ws_ahi, ws_alo, out);
    } else {
        // Fallback (R1 pipeline): scratch inside the verts region of d_out.
        bf16*  ws_pdt  = (bf16*)(out + SCRF_PDT);
        bf16*  ws_pf   = (bf16*)(out + SCRF_PF);
        float* ws_jtjs = out + SCRF_JTJS;
        k_prep2<<<3156, 256, 0, stream>>>(jreg, vt, sd, lbs, pd, ws_jtjs,
                                          nullptr, nullptr, ws_pdt);
        k_pose<<<BDIM, 64, 0, stream>>>(betas, pose, parents, ws_jtjs, out, ws_pf,
                                        nullptr, nullptr);
        k_posegemm<<<dim3(81, 32), 256, 0, stream>>>(ws_pf, ws_pdt, out + OUT_VSHAPED);
        k_lbs<<<dim3(27, BDIM/NB), 256, 0, stream>>>(betas, sd, vt, lbs, out + OUT_A, out);
    }
}

// Round 9
// 317.724 us; speedup vs baseline: 1.0275x; 1.0241x over previous
//
#include <hip/hip_runtime.h>
#include <hip/hip_bf16.h>

#define BDIM 1024
#define VDIM 6890
#define NJ   24
#define NCOL (VDIM*3)   // 20670
#define KPAD 224        // 207 padded to 7*32
#define NPAD 20736      // 108*192 = 81*256 columns, zero-padded for guardless loads
#define NB   8          // batches per k_lbs block (fallback path)
#define VPAD 6912       // 108*64 vertices, zero-padded for W fragments
#define MB   16         // batches per k_gemmlbs block

// fp32-element offsets into d_out (float*):
#define OUT_VERTS   0
#define OUT_JPOSED  21166080
#define OUT_JREST   21239808
#define OUT_A       21313536
#define OUT_VSHAPED 21706752

// Fallback-path scratch inside the verts region of d_out (dead before k_lbs
// writes verts). Offsets in fp32 elements; pdt/pf are bf16 arrays.
#define SCRF_PDT    0          // bf16 NPAD*KPAD
#define SCRF_PF     2322432    // bf16 1024*224
#define SCRF_JTJS   2437120    // 792 f32

// Workspace layout (main fused path), byte offsets:
#define WSB_PDT   0u
#define WSB_PF    9289728u                    // NPAD*KPAD*2
#define WSB_JTJS  9748480u                    // + 1024*KPAD*2
#define WSB_WHI   9752064u                    // jtjs 3168 B, aligned up
#define WSB_WLO   10194432u                   // + VPAD*32*2
#define WSB_AHI   10636800u                   // + VPAD*32*2
#define WSB_ALO   11685376u                   // + 1024*512*2
#define WS_NEED   12733952u                   // + 1024*512*2

typedef __hip_bfloat16 bf16;
typedef unsigned short ushort_t;
typedef __attribute__((ext_vector_type(8))) short  short8;
typedef __attribute__((ext_vector_type(4))) float  float4v;

__device__ __forceinline__ bf16  tob(float x) { return __float2bfloat16(x); }

// RNE float->bf16 bit helpers (self-consistent hi/lo split; finite inputs only)
__device__ __forceinline__ ushort_t bf16_rne(float x) {
    unsigned u = __builtin_bit_cast(unsigned, x);
    unsigned r = (u + 0x7FFFu + ((u >> 16) & 1u)) >> 16;
    return (ushort_t)r;
}
__device__ __forceinline__ float bf16_to_f(ushort_t h) {
    unsigned u = ((unsigned)h) << 16;
    return __builtin_bit_cast(float, u);
}

// ---------------- Kernel P2: jtjs + wpack + posedirs-transpose in ONE launch ----------------
// blocks [0,24): jtjs. [24,888): wpack (skipped if whi==null). [888,3156): transpose.
__global__ __launch_bounds__(256) void k_prep2(const float* __restrict__ jreg,
        const float* __restrict__ vt, const float* __restrict__ sd,
        const float* __restrict__ lbs, const float* __restrict__ pd,
        float* __restrict__ jtjs, ushort_t* __restrict__ whi,
        ushort_t* __restrict__ wlo, bf16* __restrict__ pdt) {
    __shared__ float red[4][33];
    __shared__ bf16 tile[32][65];
    int bid = blockIdx.x;
    int t = threadIdx.x;
    if (bid < 24) {
        // ---- jtjs: [JT|JS](24 x 33) = jreg(24 x V) @ [vt|sd](V x 33) ----
        int j = bid;
        float acc[33];
#pragma unroll
        for (int i = 0; i < 33; i++) acc[i] = 0.f;
        for (int v = t; v < VDIM; v += 256) {
            float r = jreg[j*VDIM + v];
#pragma unroll
            for (int m = 0; m < 3; m++) {
                acc[m] += r * vt[v*3+m];
#pragma unroll
                for (int l = 0; l < 10; l++)
                    acc[3 + m*10 + l] += r * sd[(v*3+m)*10 + l];
            }
        }
        int lane = t & 63, wid = t >> 6;
#pragma unroll
        for (int i = 0; i < 33; i++) {
            float x = acc[i];
            for (int off = 32; off > 0; off >>= 1) x += __shfl_down(x, off);
            if (lane == 0) red[wid][i] = x;
        }
        __syncthreads();
        if (t < 33)
            jtjs[j*33 + t] = red[0][t] + red[1][t] + red[2][t] + red[3][t];
        return;
    }
    if (bid < 888) {
        // ---- wpack: lbs_weights -> bf16 hi/lo W fragments [v][32] ----
        if (!whi) return;
        int idx = (bid - 24)*256 + t;            // < VPAD*32 exactly
        int v = idx >> 5, j = idx & 31;
        float x = (v < VDIM && j < 24) ? lbs[v*24 + j] : 0.f;
        ushort_t h = bf16_rne(x);
        whi[idx] = h;
        wlo[idx] = bf16_rne(x - bf16_to_f(h));
        return;
    }
    // ---- transpose: posedirs f32 (207 x 20670) -> bf16 (NPAD x KPAD) ----
    int r = bid - 888;
    int nt = (r % 324) * 64;
    int kt = (r / 324) * 32;
    for (int i = t; i < 32*64; i += 256) {
        int kk = i >> 6, nn = i & 63;
        int k = kt + kk, n = nt + nn;
        float v = 0.f;
        if (k < 207 && n < NCOL) v = pd[k*NCOL + n];
        tile[kk][nn] = tob(v);
    }
    __syncthreads();
    {
        int oct = t >> 6, nn = t & 63;
        short8 o;
#pragma unroll
        for (int q = 0; q < 8; q++)
            o[q] = (short)*reinterpret_cast<const ushort_t*>(&tile[oct*8 + q][nn]);
        *reinterpret_cast<short8*>((ushort_t*)pdt + (nt + nn)*KPAD + kt + oct*8) = o;
    }
}

// ---------------- Kernel B: per-batch pose (Rodrigues, chain, A, J_rest, J_posed) ----------------
__global__ __launch_bounds__(64) void k_pose(const float* __restrict__ betas,
        const float* __restrict__ pose, const int* __restrict__ parents,
        const float* __restrict__ jtjs, float* __restrict__ out,
        bf16* __restrict__ wspf, ushort_t* __restrict__ ahi,
        ushort_t* __restrict__ alo) {
    int b = blockIdx.x, t = threadIdx.x;
    __shared__ float R[24][9];
    __shared__ float jrest[24][3];
    __shared__ float rel[24][3];
    __shared__ float ch[24][12];
    __shared__ int par[24];
    if (t < 24) {
        par[t] = parents[t];
        float rx = pose[b*72 + t*3 + 0];
        float ry = pose[b*72 + t*3 + 1];
        float rz = pose[b*72 + t*3 + 2];
        float ax = rx + 1e-8f, ay = ry + 1e-8f, az = rz + 1e-8f;
        float angle = sqrtf(ax*ax + ay*ay + az*az);
        float inv = 1.0f / angle;               // axis = original r / angle (ref semantics)
        float kx = rx*inv, ky = ry*inv, kz = rz*inv;
        float s = sinf(angle), c = cosf(angle);
        float t1 = 1.0f - c;
        float q = kx*kx + ky*ky + kz*kz;        // K^2 = kk^T - (k.k) I
        R[t][0] = 1.f + t1*(kx*kx - q);
        R[t][1] = -s*kz + t1*kx*ky;
        R[t][2] =  s*ky + t1*kx*kz;
        R[t][3] =  s*kz + t1*kx*ky;
        R[t][4] = 1.f + t1*(ky*ky - q);
        R[t][5] = -s*kx + t1*ky*kz;
        R[t][6] = -s*ky + t1*kx*kz;
        R[t][7] =  s*kx + t1*ky*kz;
        R[t][8] = 1.f + t1*(kz*kz - q);
    }
    __syncthreads();
    // pose_feature -> scratch (bf16, zero-padded to KPAD)
    for (int i = t; i < KPAD; i += 64) {
        float pf = 0.f;
        if (i < 207) {
            int j = i/9 + 1, e = i - (j-1)*9;
            pf = R[j][e] - ((e == 0 || e == 4 || e == 8) ? 1.f : 0.f);
        }
        wspf[b*KPAD + i] = tob(pf);
    }
    // J_rest = JT + JS . betas
    for (int i = t; i < 72; i += 64) {
        int j = i/3, k = i - j*3;
        const float* JJ = &jtjs[j*33];
        float s = JJ[k];
#pragma unroll
        for (int l = 0; l < 10; l++) s += JJ[3 + k*10 + l] * betas[b*10 + l];
        jrest[j][k] = s;
        out[OUT_JREST + b*72 + i] = s;
    }
    __syncthreads();
    for (int i = t; i < 72; i += 64) {
        int j = i/3, k = i - j*3;
        rel[j][k] = jrest[j][k] - (j > 0 ? jrest[par[j]][k] : 0.f);
    }
    __syncthreads();
    if (t < 12) {
        int m = t >> 2, n = t & 3;
        ch[0][t] = (n < 3) ? R[0][m*3+n] : rel[0][m];
    }
    __syncthreads();
    for (int i = 1; i < 24; i++) {
        float val = 0.f;
        if (t < 12) {
            int m = t >> 2, n = t & 3;
            int p = par[i];                      // p < i: no overlap with ch[i] write
            if (n < 3)
                val = ch[p][m*4+0]*R[i][n] + ch[p][m*4+1]*R[i][3+n] + ch[p][m*4+2]*R[i][6+n];
            else
                val = ch[p][m*4+0]*rel[i][0] + ch[p][m*4+1]*rel[i][1]
                    + ch[p][m*4+2]*rel[i][2] + ch[p][m*4+3];
        }
        if (t < 12) ch[i][t] = val;
        __syncthreads();
    }
    for (int i = t; i < 72; i += 64) {
        int j = i/3, k = i - j*3;
        out[OUT_JPOSED + b*72 + i] = ch[j][k*4+3];
    }
    // A = chain with translation t - R*jrest (fp32 output; consumers re-read it)
    for (int i = t; i < 384; i += 64) {
        int j = i >> 4, e = i & 15, m = e >> 2, n = e & 3;
        float v;
        if (m < 3) {
            if (n < 3) v = ch[j][m*4+n];
            else v = ch[j][m*4+3] - (ch[j][m*4+0]*jrest[j][0] + ch[j][m*4+1]*jrest[j][1]
                                   + ch[j][m*4+2]*jrest[j][2]);
        } else v = (n == 3) ? 1.f : 0.f;
        out[OUT_A + b*384 + i] = v;
    }
    // A bf16 hi/lo MFMA fragments: [b][e(16)][j(32)], zero-padded.
    if (ahi) {
        for (int i = t; i < 512; i += 64) {
            int e = i >> 5, j = i & 31;
            float v = 0.f;
            if (j < 24 && e < 12) {
                int m = e >> 2, n = e & 3;
                if (n < 3) v = ch[j][m*4+n];
                else v = ch[j][m*4+3] - (ch[j][m*4+0]*jrest[j][0] + ch[j][m*4+1]*jrest[j][1]
                                       + ch[j][m*4+2]*jrest[j][2]);
            }
            ushort_t h = bf16_rne(v);
            ahi[b*512 + i] = h;
            alo[b*512 + i] = bf16_rne(v - bf16_to_f(h));
        }
    }
}

// ---------------- Kernel F (main path): fused pose-GEMM + LBS, all-MFMA ----------------
// R8: XCD-locality swizzle. R7 falsified the store-path theory (FETCH/WRITE
// unchanged); the 106MB over-fetch scales with block count = shared-read
// re-requests (pdt ~600MB of L2 read traffic) falling through to HBM because
// the 198MB write stream evicts them from L2/L3. Also the kernel is HBM-
// latency/MLP-bound (2.65 TB/s at 75% occ, all pipes <16%). Fix: 1-D grid +
// bijective remap f->(vt,bg): xcd=f&7, i=f>>3, vt=i>>3, bg=(i&7)|(xcd<<3).
// Under round-robin dispatch each XCD's ~256 resident blocks span 8 batch-
// groups x ~32 vertex-tiles: pdt window 2.75MB + A 0.26MB + W/sd 0.3MB < 4MB
// L2 -> re-reads become L2 hits (fewer HBM bytes AND lower latency). Body
// unchanged -> bit-identical outputs.
__global__ __launch_bounds__(256, 8) void k_gemmlbs(const bf16* __restrict__ wspf,
        const bf16* __restrict__ wspdt, const float* __restrict__ betas,
        const float* __restrict__ sd, const float* __restrict__ vt,
        const ushort_t* __restrict__ whi, const ushort_t* __restrict__ wlo,
        const ushort_t* __restrict__ ahi, const ushort_t* __restrict__ alo,
        float* __restrict__ out) {
    __shared__ float dtile[MB][260];
    const ushort_t* pf  = (const ushort_t*)wspf;
    const ushort_t* pdt = (const ushort_t*)wspdt;
    int tid  = threadIdx.x;
    int lane = tid & 63, wave = tid >> 6;
    int l15 = lane & 15, quad = lane >> 4;
    // XCD-aware bijective swizzle (perf-only; correctness independent of mapping)
    int f   = blockIdx.x;              // 0..6911
    int xcd = f & 7, ii = f >> 3;      // ii: 0..863
    int vtile = ii >> 3;               // 0..107
    int bg    = (ii & 7) | (xcd << 3); // 0..63
    int m0 = bg * MB;                  // batch base
    int v0 = vtile * 64;               // vertex base
    int cb = wave * 48;                // wave's col base within tile
    int colb = v0*3 + cb;              // global col base (max 20735 < NPAD)
    int wv = __builtin_amdgcn_readfirstlane(wave);   // provably uniform batch group

    // ---- Phase 1: pose-delta GEMM (bf16 K=224), 16 batch rows ----
    {
        float4v acc[3] = {};
        for (int c = 0; c < 7; c++) {
            short8 a = *reinterpret_cast<const short8*>(pf + (m0 + l15)*KPAD + c*32 + quad*8);
            short8 bb[3];
#pragma unroll
            for (int nf = 0; nf < 3; nf++)
                bb[nf] = *reinterpret_cast<const short8*>(pdt + (colb + nf*16 + l15)*KPAD + c*32 + quad*8);
#pragma unroll
            for (int nf = 0; nf < 3; nf++)
                acc[nf] = __builtin_amdgcn_mfma_f32_16x16x32_bf16(a, bb[nf], acc[nf], 0, 0, 0);
        }
#pragma unroll
        for (int nf = 0; nf < 3; nf++) {
            int c0 = cb + nf*16 + l15;           // col in [0,192)
            int vv = c0 / 3, rr = c0 - vv*3;     // vertex-in-tile, component
            int ad = vv*4 + rr;                  // padded float4 slot
#pragma unroll
            for (int r = 0; r < 4; r++)
                dtile[quad*4 + r][ad] = acc[nf][r];
        }
    }
    __syncthreads();

    // ---- Phase 2: vs, vp in-place (b128 RMW), vsh (lane = vertex, 4 batches/wave) ----
    int v = v0 + lane;
    float* vsh = out + OUT_VSHAPED;
    if (v < VDIM) {
        float vtv[3];
#pragma unroll
        for (int m = 0; m < 3; m++) vtv[m] = vt[v*3 + m];
        float sdv[30];
#pragma unroll
        for (int i = 0; i < 30; i++) sdv[i] = sd[v*30 + i];
#pragma unroll 2
        for (int bb2 = 0; bb2 < 4; bb2++) {
            int b  = m0 + wv*4 + bb2;                // scalar
            int bl = wv*4 + bb2;
            float vs[3];
#pragma unroll
            for (int m = 0; m < 3; m++) {
                float s = vtv[m];
#pragma unroll
                for (int l = 0; l < 10; l++) s += betas[b*10 + l] * sdv[m*10 + l];
                vs[m] = s;
            }
            float4v* slot = reinterpret_cast<float4v*>(&dtile[bl][lane*4]);
            float4v d = *slot;
            float4v vp;
            vp[0] = vs[0] + d[0]; vp[1] = vs[1] + d[1];
            vp[2] = vs[2] + d[2]; vp[3] = 0.f;
            *slot = vp;
            int base = b*NCOL + v*3;
#pragma unroll
            for (int n = 0; n < 3; n++) vsh[base + n] = vs[n];
        }
    }
    // NOTE: no barrier -- dtile rows [wv*4, wv*4+4) are wave-private from here.

    // ---- Phase 3: T via 3-split MFMA (precomputed A-frags); o -> LDS slot ----
    short8 bhi[4], blo[4];
#pragma unroll
    for (int nf = 0; nf < 4; nf++) {
        int vv = v0 + nf*16 + l15;                   // < VPAD, padded
        bhi[nf] = *reinterpret_cast<const short8*>(whi + vv*32 + quad*8);
        blo[nf] = *reinterpret_cast<const short8*>(wlo + vv*32 + quad*8);
    }
    const ushort_t* ah = ahi + (size_t)(m0 + wv*4)*512 + l15*32 + quad*8;
    const ushort_t* al = alo + (size_t)(m0 + wv*4)*512 + l15*32 + quad*8;
#pragma unroll 1
    for (int bb2 = 0; bb2 < 4; bb2++) {
        int bl = wv*4 + bb2;
        short8 a_hi = *reinterpret_cast<const short8*>(ah + (size_t)bb2*512);
        short8 a_lo = *reinterpret_cast<const short8*>(al + (size_t)bb2*512);
#pragma unroll
        for (int nf = 0; nf < 4; nf++) {
            float4v acc = {};
            acc = __builtin_amdgcn_mfma_f32_16x16x32_bf16(a_hi, bhi[nf], acc, 0, 0, 0);
            acc = __builtin_amdgcn_mfma_f32_16x16x32_bf16(a_lo, bhi[nf], acc, 0, 0, 0);
            acc = __builtin_amdgcn_mfma_f32_16x16x32_bf16(a_hi, blo[nf], acc, 0, 0, 0);
            int vl = nf*16 + l15;
            // lockstep: all lanes' vp reads issue before any o write
            float4v vp = *reinterpret_cast<const float4v*>(&dtile[bl][vl*4]);
            if (quad < 3) {
                // acc[r]: row e = quad*4+r -> T[m=quad][n=r]
                float o = acc[3] + acc[0]*vp[0] + acc[1]*vp[1] + acc[2]*vp[2];
                dtile[bl][vl*4 + quad] = o;          // park in spare-word slot
            }
        }
    }

    // ---- Phase 4: contiguous verts write-out (lane = vertex, full lines) ----
    if (v < VDIM) {
#pragma unroll
        for (int bb2 = 0; bb2 < 4; bb2++) {
            int b  = m0 + wv*4 + bb2;
            int bl = wv*4 + bb2;
            float4v o = *reinterpret_cast<const float4v*>(&dtile[bl][lane*4]);
            int base = b*NCOL + v*3;
            out[base + 0] = o[0];
            out[base + 1] = o[1];
            out[base + 2] = o[2];
        }
    }
}

// ---------------- Fallback kernels (ws too small): R1 pipeline ----------------
__global__ __launch_bounds__(256) void k_posegemm(const bf16* __restrict__ wspf,
        const bf16* __restrict__ wspdt, float* __restrict__ dout) {
    const ushort_t* pf  = (const ushort_t*)wspf;
    const ushort_t* pdt = (const ushort_t*)wspdt;
    int lane = threadIdx.x & 63;
    int wave = threadIdx.x >> 6;
    int l15 = lane & 15, quad = lane >> 4;
    int m0 = blockIdx.y * 32;
    int n0 = blockIdx.x * 256 + wave * 64;
    float4v acc[2][4] = {};
    for (int c = 0; c < 7; c++) {
        short8 a[2], bb[4];
#pragma unroll
        for (int mf = 0; mf < 2; mf++)
            a[mf] = *reinterpret_cast<const short8*>(pf + (m0 + mf*16 + l15)*KPAD + c*32 + quad*8);
#pragma unroll
        for (int nf = 0; nf < 4; nf++)
            bb[nf] = *reinterpret_cast<const short8*>(pdt + (n0 + nf*16 + l15)*KPAD + c*32 + quad*8);
#pragma unroll
        for (int mf = 0; mf < 2; mf++)
#pragma unroll
            for (int nf = 0; nf < 4; nf++)
                acc[mf][nf] = __builtin_amdgcn_mfma_f32_16x16x32_bf16(a[mf], bb[nf], acc[mf][nf], 0, 0, 0);
    }
#pragma unroll
    for (int mf = 0; mf < 2; mf++)
#pragma unroll
        for (int nf = 0; nf < 4; nf++) {
            int col = n0 + nf*16 + l15;
            if (col < NCOL) {
#pragma unroll
                for (int r = 0; r < 4; r++) {
                    int row = m0 + mf*16 + quad*4 + r;
                    dout[row*NCOL + col] = acc[mf][nf][r];
                }
            }
        }
}

__global__ __launch_bounds__(256) void k_lbs(const float* __restrict__ betas,
        const float* __restrict__ sd, const float* __restrict__ vt,
        const float* __restrict__ lbs, const float* __restrict__ Amat,
        float* __restrict__ out) {
    int tid = threadIdx.x;
    int v = blockIdx.x*256 + tid;
    if (v >= VDIM) return;
    int b0 = blockIdx.y * NB;
    float w[24];
    {
        const float4v* W4 = reinterpret_cast<const float4v*>(lbs + v*24);
#pragma unroll
        for (int q = 0; q < 6; q++) {
            float4v x = W4[q];
#pragma unroll
            for (int e = 0; e < 4; e++) w[q*4+e] = x[e];
        }
    }
    float vtv[3];
#pragma unroll
    for (int m = 0; m < 3; m++) vtv[m] = vt[v*3 + m];
    float sdv[30];
#pragma unroll
    for (int i = 0; i < 30; i++) sdv[i] = sd[v*30 + i];
    float* vsh = out + OUT_VSHAPED;
#pragma unroll 1
    for (int bb = 0; bb < NB; bb++) {
        int b = b0 + bb;
        const float* __restrict__ Ab = Amat + (size_t)b*384;
        float T[12];
#pragma unroll
        for (int e = 0; e < 12; e++) T[e] = 0.f;
#pragma unroll
        for (int j = 0; j < 24; j++) {
#pragma unroll
            for (int e = 0; e < 12; e++)
                T[e] = fmaf(w[j], Ab[j*16 + e], T[e]);
        }
        float vs[3];
#pragma unroll
        for (int m = 0; m < 3; m++) {
            float s = vtv[m];
#pragma unroll
            for (int l = 0; l < 10; l++) s += betas[b*10 + l] * sdv[m*10 + l];
            vs[m] = s;
        }
        int base = b*NCOL + v*3;
        float vp0 = vs[0] + vsh[base + 0];
        float vp1 = vs[1] + vsh[base + 1];
        float vp2 = vs[2] + vsh[base + 2];
#pragma unroll
        for (int m = 0; m < 3; m++) {
            float o = T[m*4+3] + T[m*4]*vp0 + T[m*4+1]*vp1 + T[m*4+2]*vp2;
            out[base + m] = o;
            vsh[base + m] = vs[m];
        }
    }
}

extern "C" void kernel_launch(void* const* d_in, const int* in_sizes, int n_in,
                              void* d_out, int out_size, void* d_ws, size_t ws_size,
                              hipStream_t stream) {
    const float *betas = nullptr, *pose = nullptr, *vt = nullptr, *sd = nullptr,
                *pd = nullptr, *jreg = nullptr, *lbs = nullptr;
    const int* parents = nullptr;
    for (int i = 0; i < n_in; i++) {
        switch (in_sizes[i]) {
            case 10240:   betas = (const float*)d_in[i]; break;      // (1024,10)
            case 73728:   pose  = (const float*)d_in[i]; break;      // (1024,72)
            case 20670:   vt    = (const float*)d_in[i]; break;      // (1,6890,3)
            case 206700:  sd    = (const float*)d_in[i]; break;      // (6890,3,10)
            case 4278690: pd    = (const float*)d_in[i]; break;      // (207,20670)
            case 24:      parents = (const int*)d_in[i]; break;      // (24,)
            case 165360:                                             // (24,6890)/(6890,24)
                if (!jreg) jreg = (const float*)d_in[i];
                else       lbs  = (const float*)d_in[i];
                break;
            default: break;
        }
    }
    float* out = (float*)d_out;
    if (d_ws && ws_size >= (size_t)WS_NEED) {
        // Main path: scratch in workspace; fused all-MFMA GEMM+LBS.
        bf16*     ws_pdt  = (bf16*)((char*)d_ws + WSB_PDT);
        bf16*     ws_pf   = (bf16*)((char*)d_ws + WSB_PF);
        float*    ws_jtjs = (float*)((char*)d_ws + WSB_JTJS);
        ushort_t* ws_whi  = (ushort_t*)((char*)d_ws + WSB_WHI);
        ushort_t* ws_wlo  = (ushort_t*)((char*)d_ws + WSB_WLO);
        ushort_t* ws_ahi  = (ushort_t*)((char*)d_ws + WSB_AHI);
        ushort_t* ws_alo  = (ushort_t*)((char*)d_ws + WSB_ALO);
        k_prep2<<<3156, 256, 0, stream>>>(jreg, vt, sd, lbs, pd, ws_jtjs,
                                          ws_whi, ws_wlo, ws_pdt);
        k_pose<<<BDIM, 64, 0, stream>>>(betas, pose, parents, ws_jtjs, out, ws_pf,
                                        ws_ahi, ws_alo);
        k_gemmlbs<<<108*64, 256, 0, stream>>>(ws_pf, ws_pdt, betas, sd, vt,
                                              ws_whi, ws_wlo, ws_ahi, ws_alo, out);
    } else {
        // Fallback (R1 pipeline): scratch inside the verts region of d_out.
        bf16*  ws_pdt  = (bf16*)(out + SCRF_PDT);
        bf16*  ws_pf   = (bf16*)(out + SCRF_PF);
        float* ws_jtjs = out + SCRF_JTJS;
        k_prep2<<<3156, 256, 0, stream>>>(jreg, vt, sd, lbs, pd, ws_jtjs,
                                          nullptr, nullptr, ws_pdt);
        k_pose<<<BDIM, 64, 0, stream>>>(betas, pose, parents, ws_jtjs, out, ws_pf,
                                        nullptr, nullptr);
        k_posegemm<<<dim3(81, 32), 256, 0, stream>>>(ws_pf, ws_pdt, out + OUT_VSHAPED);
        k_lbs<<<dim3(27, BDIM/NB), 256, 0, stream>>>(betas, sd, vt, lbs, out + OUT_A, out);
    }
}

// Round 10
// 282.451 us; speedup vs baseline: 1.1558x; 1.1249x over previous
//
#include <hip/hip_runtime.h>
#include <hip/hip_bf16.h>

#define BDIM 1024
#define VDIM 6890
#define NJ   24
#define NCOL (VDIM*3)   // 20670
#define KPAD 224        // 207 padded to 7*32
#define NPAD 20736      // 108*192 = 81*256 columns, zero-padded for guardless loads
#define NB   8          // batches per k_lbs block (fallback path)
#define VPAD 6912       // 108*64 vertices, zero-padded for W fragments
#define MB   32         // batches per k_gemmlbs block (R9: back to 32, best measured)

// fp32-element offsets into d_out (float*):
#define OUT_VERTS   0
#define OUT_JPOSED  21166080
#define OUT_JREST   21239808
#define OUT_A       21313536
#define OUT_VSHAPED 21706752

// Fallback-path scratch inside the verts region of d_out (dead before k_lbs
// writes verts). Offsets in fp32 elements; pdt/pf are bf16 arrays.
#define SCRF_PDT    0          // bf16 NPAD*KPAD
#define SCRF_PF     2322432    // bf16 1024*224
#define SCRF_JTJS   2437120    // 792 f32

// Workspace layout (main fused path), byte offsets:
#define WSB_PDT   0u
#define WSB_PF    9289728u                    // NPAD*KPAD*2
#define WSB_JTJS  9748480u                    // + 1024*KPAD*2
#define WSB_WHI   9752064u                    // jtjs 3168 B, aligned up
#define WSB_WLO   10194432u                   // + VPAD*32*2
#define WSB_AHI   10636800u                   // + VPAD*32*2
#define WSB_ALO   11685376u                   // + 1024*512*2
#define WS_NEED   12733952u                   // + 1024*512*2

typedef __hip_bfloat16 bf16;
typedef unsigned short ushort_t;
typedef __attribute__((ext_vector_type(8))) short  short8;
typedef __attribute__((ext_vector_type(4))) float  float4v;

__device__ __forceinline__ bf16  tob(float x) { return __float2bfloat16(x); }

// RNE float->bf16 bit helpers (self-consistent hi/lo split; finite inputs only)
__device__ __forceinline__ ushort_t bf16_rne(float x) {
    unsigned u = __builtin_bit_cast(unsigned, x);
    unsigned r = (u + 0x7FFFu + ((u >> 16) & 1u)) >> 16;
    return (ushort_t)r;
}
__device__ __forceinline__ float bf16_to_f(ushort_t h) {
    unsigned u = ((unsigned)h) << 16;
    return __builtin_bit_cast(float, u);
}

// ---------------- Kernel P2: jtjs + wpack + posedirs-transpose in ONE launch ----------------
// blocks [0,24): jtjs. [24,888): wpack (skipped if whi==null). [888,3156): transpose.
__global__ __launch_bounds__(256) void k_prep2(const float* __restrict__ jreg,
        const float* __restrict__ vt, const float* __restrict__ sd,
        const float* __restrict__ lbs, const float* __restrict__ pd,
        float* __restrict__ jtjs, ushort_t* __restrict__ whi,
        ushort_t* __restrict__ wlo, bf16* __restrict__ pdt) {
    __shared__ float red[4][33];
    __shared__ bf16 tile[32][65];
    int bid = blockIdx.x;
    int t = threadIdx.x;
    if (bid < 24) {
        // ---- jtjs: [JT|JS](24 x 33) = jreg(24 x V) @ [vt|sd](V x 33) ----
        int j = bid;
        float acc[33];
#pragma unroll
        for (int i = 0; i < 33; i++) acc[i] = 0.f;
        for (int v = t; v < VDIM; v += 256) {
            float r = jreg[j*VDIM + v];
#pragma unroll
            for (int m = 0; m < 3; m++) {
                acc[m] += r * vt[v*3+m];
#pragma unroll
                for (int l = 0; l < 10; l++)
                    acc[3 + m*10 + l] += r * sd[(v*3+m)*10 + l];
            }
        }
        int lane = t & 63, wid = t >> 6;
#pragma unroll
        for (int i = 0; i < 33; i++) {
            float x = acc[i];
            for (int off = 32; off > 0; off >>= 1) x += __shfl_down(x, off);
            if (lane == 0) red[wid][i] = x;
        }
        __syncthreads();
        if (t < 33)
            jtjs[j*33 + t] = red[0][t] + red[1][t] + red[2][t] + red[3][t];
        return;
    }
    if (bid < 888) {
        // ---- wpack: lbs_weights -> bf16 hi/lo W fragments [v][32] ----
        if (!whi) return;
        int idx = (bid - 24)*256 + t;            // < VPAD*32 exactly
        int v = idx >> 5, j = idx & 31;
        float x = (v < VDIM && j < 24) ? lbs[v*24 + j] : 0.f;
        ushort_t h = bf16_rne(x);
        whi[idx] = h;
        wlo[idx] = bf16_rne(x - bf16_to_f(h));
        return;
    }
    // ---- transpose: posedirs f32 (207 x 20670) -> bf16 (NPAD x KPAD) ----
    int r = bid - 888;
    int nt = (r % 324) * 64;
    int kt = (r / 324) * 32;
    for (int i = t; i < 32*64; i += 256) {
        int kk = i >> 6, nn = i & 63;
        int k = kt + kk, n = nt + nn;
        float v = 0.f;
        if (k < 207 && n < NCOL) v = pd[k*NCOL + n];
        tile[kk][nn] = tob(v);
    }
    __syncthreads();
    {
        int oct = t >> 6, nn = t & 63;
        short8 o;
#pragma unroll
        for (int q = 0; q < 8; q++)
            o[q] = (short)*reinterpret_cast<const ushort_t*>(&tile[oct*8 + q][nn]);
        *reinterpret_cast<short8*>((ushort_t*)pdt + (nt + nn)*KPAD + kt + oct*8) = o;
    }
}

// ---------------- Kernel B: per-batch pose, one batch PER WAVE ----------------
// R9: 256-thread blocks = 4 batches; each wave handles one batch in lockstep,
// shared arrays indexed [wave] -> all __syncthreads removed (the 24-iteration
// chain had a barrier per iteration). Same per-batch arithmetic -> bit-identical.
__global__ __launch_bounds__(256) void k_pose(const float* __restrict__ betas,
        const float* __restrict__ pose, const int* __restrict__ parents,
        const float* __restrict__ jtjs, float* __restrict__ out,
        bf16* __restrict__ wspf, ushort_t* __restrict__ ahi,
        ushort_t* __restrict__ alo) {
    int wave = threadIdx.x >> 6, t = threadIdx.x & 63;
    int b = blockIdx.x*4 + wave;
    __shared__ float R[4][24][9];
    __shared__ float jrest[4][24][3];
    __shared__ float rel[4][24][3];
    __shared__ float ch[4][24][12];
    __shared__ int par[4][24];
    if (t < 24) {
        par[wave][t] = parents[t];
        float rx = pose[b*72 + t*3 + 0];
        float ry = pose[b*72 + t*3 + 1];
        float rz = pose[b*72 + t*3 + 2];
        float ax = rx + 1e-8f, ay = ry + 1e-8f, az = rz + 1e-8f;
        float angle = sqrtf(ax*ax + ay*ay + az*az);
        float inv = 1.0f / angle;               // axis = original r / angle (ref semantics)
        float kx = rx*inv, ky = ry*inv, kz = rz*inv;
        float s = sinf(angle), c = cosf(angle);
        float t1 = 1.0f - c;
        float q = kx*kx + ky*ky + kz*kz;        // K^2 = kk^T - (k.k) I
        R[wave][t][0] = 1.f + t1*(kx*kx - q);
        R[wave][t][1] = -s*kz + t1*kx*ky;
        R[wave][t][2] =  s*ky + t1*kx*kz;
        R[wave][t][3] =  s*kz + t1*kx*ky;
        R[wave][t][4] = 1.f + t1*(ky*ky - q);
        R[wave][t][5] = -s*kx + t1*ky*kz;
        R[wave][t][6] = -s*ky + t1*kx*kz;
        R[wave][t][7] =  s*kx + t1*ky*kz;
        R[wave][t][8] = 1.f + t1*(kz*kz - q);
    }
    // (wave-lockstep: LDS deps within a wave are ordered by compiler lgkmcnt)
    // pose_feature -> scratch (bf16, zero-padded to KPAD)
    for (int i = t; i < KPAD; i += 64) {
        float pf = 0.f;
        if (i < 207) {
            int j = i/9 + 1, e = i - (j-1)*9;
            pf = R[wave][j][e] - ((e == 0 || e == 4 || e == 8) ? 1.f : 0.f);
        }
        wspf[b*KPAD + i] = tob(pf);
    }
    // J_rest = JT + JS . betas
    for (int i = t; i < 72; i += 64) {
        int j = i/3, k = i - j*3;
        const float* JJ = &jtjs[j*33];
        float s = JJ[k];
#pragma unroll
        for (int l = 0; l < 10; l++) s += JJ[3 + k*10 + l] * betas[b*10 + l];
        jrest[wave][j][k] = s;
        out[OUT_JREST + b*72 + i] = s;
    }
    for (int i = t; i < 72; i += 64) {
        int j = i/3, k = i - j*3;
        rel[wave][j][k] = jrest[wave][j][k] - (j > 0 ? jrest[wave][par[wave][j]][k] : 0.f);
    }
    if (t < 12) {
        int m = t >> 2, n = t & 3;
        ch[wave][0][t] = (n < 3) ? R[wave][0][m*3+n] : rel[wave][0][m];
    }
    for (int i = 1; i < 24; i++) {
        if (t < 12) {
            int m = t >> 2, n = t & 3;
            int p = par[wave][i];                // p < i: no overlap with ch[i] write
            float val;
            if (n < 3)
                val = ch[wave][p][m*4+0]*R[wave][i][n] + ch[wave][p][m*4+1]*R[wave][i][3+n]
                    + ch[wave][p][m*4+2]*R[wave][i][6+n];
            else
                val = ch[wave][p][m*4+0]*rel[wave][i][0] + ch[wave][p][m*4+1]*rel[wave][i][1]
                    + ch[wave][p][m*4+2]*rel[wave][i][2] + ch[wave][p][m*4+3];
            ch[wave][i][t] = val;
        }
    }
    for (int i = t; i < 72; i += 64) {
        int j = i/3, k = i - j*3;
        out[OUT_JPOSED + b*72 + i] = ch[wave][j][k*4+3];
    }
    // A = chain with translation t - R*jrest (fp32 output; consumers re-read it)
    for (int i = t; i < 384; i += 64) {
        int j = i >> 4, e = i & 15, m = e >> 2, n = e & 3;
        float v;
        if (m < 3) {
            if (n < 3) v = ch[wave][j][m*4+n];
            else v = ch[wave][j][m*4+3] - (ch[wave][j][m*4+0]*jrest[wave][j][0]
                   + ch[wave][j][m*4+1]*jrest[wave][j][1]
                   + ch[wave][j][m*4+2]*jrest[wave][j][2]);
        } else v = (n == 3) ? 1.f : 0.f;
        out[OUT_A + b*384 + i] = v;
    }
    // A bf16 hi/lo MFMA fragments: [b][e(16)][j(32)], zero-padded.
    if (ahi) {
        for (int i = t; i < 512; i += 64) {
            int e = i >> 5, j = i & 31;
            float v = 0.f;
            if (j < 24 && e < 12) {
                int m = e >> 2, n = e & 3;
                if (n < 3) v = ch[wave][j][m*4+n];
                else v = ch[wave][j][m*4+3] - (ch[wave][j][m*4+0]*jrest[wave][j][0]
                       + ch[wave][j][m*4+1]*jrest[wave][j][1]
                       + ch[wave][j][m*4+2]*jrest[wave][j][2]);
            }
            ushort_t h = bf16_rne(v);
            ahi[b*512 + i] = h;
            alo[b*512 + i] = bf16_rne(v - bf16_to_f(h));
        }
    }
}

// ---------------- Kernel F (main path): fused pose-GEMM + LBS, all-MFMA ----------------
// R9: MB=32 (best measured: R4/R5 ~95us vs MB=16's 116-125) + XCD swizzle kept
// (halved FETCH in R8). 3456 blocks = 432/XCD; bijective f->(vtile,bg):
// xcd=f&7, i=f>>3, vtile=i>>2, bg=(i&3)|(xcd<<2). Per-XCD working set
// (pdt window + 4bg A-frags + W/sd) ~2MB < 4MB L2. launch_bounds(256,4):
// LDS 33.3KB -> 4 blocks/CU (R4/R5 showed this occupancy is sufficient).
__global__ __launch_bounds__(256, 4) void k_gemmlbs(const bf16* __restrict__ wspf,
        const bf16* __restrict__ wspdt, const float* __restrict__ betas,
        const float* __restrict__ sd, const float* __restrict__ vt,
        const ushort_t* __restrict__ whi, const ushort_t* __restrict__ wlo,
        const ushort_t* __restrict__ ahi, const ushort_t* __restrict__ alo,
        float* __restrict__ out) {
    __shared__ float dtile[MB][260];
    const ushort_t* pf  = (const ushort_t*)wspf;
    const ushort_t* pdt = (const ushort_t*)wspdt;
    int tid  = threadIdx.x;
    int lane = tid & 63, wave = tid >> 6;
    int l15 = lane & 15, quad = lane >> 4;
    // XCD-aware bijective swizzle (perf-only; correctness independent of mapping)
    int f   = blockIdx.x;              // 0..3455
    int xcd = f & 7, ii = f >> 3;      // ii: 0..431
    int vtile = ii >> 2;               // 0..107
    int bg    = (ii & 3) | (xcd << 2); // 0..31
    int m0 = bg * MB;                  // batch base
    int v0 = vtile * 64;               // vertex base
    int cb = wave * 48;                // wave's col base within tile
    int colb = v0*3 + cb;              // global col base (max 20735 < NPAD)
    int wv = __builtin_amdgcn_readfirstlane(wave);   // provably uniform batch group

    // ---- Phase 1: pose-delta GEMM (bf16 K=224), 32 batch rows ----
    {
        float4v acc[2][3] = {};
        for (int c = 0; c < 7; c++) {
            short8 a[2], bb[3];
#pragma unroll
            for (int mf = 0; mf < 2; mf++)
                a[mf] = *reinterpret_cast<const short8*>(pf + (m0 + mf*16 + l15)*KPAD + c*32 + quad*8);
#pragma unroll
            for (int nf = 0; nf < 3; nf++)
                bb[nf] = *reinterpret_cast<const short8*>(pdt + (colb + nf*16 + l15)*KPAD + c*32 + quad*8);
#pragma unroll
            for (int mf = 0; mf < 2; mf++)
#pragma unroll
                for (int nf = 0; nf < 3; nf++)
                    acc[mf][nf] = __builtin_amdgcn_mfma_f32_16x16x32_bf16(a[mf], bb[nf], acc[mf][nf], 0, 0, 0);
        }
#pragma unroll
        for (int nf = 0; nf < 3; nf++) {
            int c0 = cb + nf*16 + l15;           // col in [0,192)
            int vv = c0 / 3, rr = c0 - vv*3;     // vertex-in-tile, component
            int ad = vv*4 + rr;                  // padded float4 slot
#pragma unroll
            for (int mf = 0; mf < 2; mf++)
#pragma unroll
                for (int r = 0; r < 4; r++)
                    dtile[mf*16 + quad*4 + r][ad] = acc[mf][nf][r];
        }
    }
    __syncthreads();

    // ---- Phase 2: vs, vp in-place (b128 RMW), vsh (lane = vertex, 8 batches/wave) ----
    int v = v0 + lane;
    float* vsh = out + OUT_VSHAPED;
    if (v < VDIM) {
        float vtv[3];
#pragma unroll
        for (int m = 0; m < 3; m++) vtv[m] = vt[v*3 + m];
        float sdv[30];
#pragma unroll
        for (int i = 0; i < 30; i++) sdv[i] = sd[v*30 + i];
#pragma unroll 2
        for (int bb2 = 0; bb2 < 8; bb2++) {
            int b  = m0 + wv*8 + bb2;                // scalar
            int bl = wv*8 + bb2;
            float vs[3];
#pragma unroll
            for (int m = 0; m < 3; m++) {
                float s = vtv[m];
#pragma unroll
                for (int l = 0; l < 10; l++) s += betas[b*10 + l] * sdv[m*10 + l];
                vs[m] = s;
            }
            float4v* slot = reinterpret_cast<float4v*>(&dtile[bl][lane*4]);
            float4v d = *slot;
            float4v vp;
            vp[0] = vs[0] + d[0]; vp[1] = vs[1] + d[1];
            vp[2] = vs[2] + d[2]; vp[3] = 0.f;
            *slot = vp;
            int base = b*NCOL + v*3;
#pragma unroll
            for (int n = 0; n < 3; n++) vsh[base + n] = vs[n];
        }
    }
    // NOTE: no barrier -- dtile rows [wv*8, wv*8+8) are wave-private from here.

    // ---- Phase 3: T via 3-split MFMA (precomputed A-frags); o -> LDS slot ----
    short8 bhi[4], blo[4];
#pragma unroll
    for (int nf = 0; nf < 4; nf++) {
        int vv = v0 + nf*16 + l15;                   // < VPAD, padded
        bhi[nf] = *reinterpret_cast<const short8*>(whi + vv*32 + quad*8);
        blo[nf] = *reinterpret_cast<const short8*>(wlo + vv*32 + quad*8);
    }
    const ushort_t* ah = ahi + (size_t)(m0 + wv*8)*512 + l15*32 + quad*8;
    const ushort_t* al = alo + (size_t)(m0 + wv*8)*512 + l15*32 + quad*8;
#pragma unroll 1
    for (int bb2 = 0; bb2 < 8; bb2++) {
        int bl = wv*8 + bb2;
        short8 a_hi = *reinterpret_cast<const short8*>(ah + (size_t)bb2*512);
        short8 a_lo = *reinterpret_cast<const short8*>(al + (size_t)bb2*512);
#pragma unroll
        for (int nf = 0; nf < 4; nf++) {
            float4v acc = {};
            acc = __builtin_amdgcn_mfma_f32_16x16x32_bf16(a_hi, bhi[nf], acc, 0, 0, 0);
            acc = __builtin_amdgcn_mfma_f32_16x16x32_bf16(a_lo, bhi[nf], acc, 0, 0, 0);
            acc = __builtin_amdgcn_mfma_f32_16x16x32_bf16(a_hi, blo[nf], acc, 0, 0, 0);
            int vl = nf*16 + l15;
            // lockstep: all lanes' vp reads issue before any o write
            float4v vp = *reinterpret_cast<const float4v*>(&dtile[bl][vl*4]);
            if (quad < 3) {
                // acc[r]: row e = quad*4+r -> T[m=quad][n=r]
                float o = acc[3] + acc[0]*vp[0] + acc[1]*vp[1] + acc[2]*vp[2];
                dtile[bl][vl*4 + quad] = o;          // park in spare-word slot
            }
        }
    }

    // ---- Phase 4: contiguous verts write-out (lane = vertex, full lines) ----
    if (v < VDIM) {
#pragma unroll
        for (int bb2 = 0; bb2 < 8; bb2++) {
            int b  = m0 + wv*8 + bb2;
            int bl = wv*8 + bb2;
            float4v o = *reinterpret_cast<const float4v*>(&dtile[bl][lane*4]);
            int base = b*NCOL + v*3;
            out[base + 0] = o[0];
            out[base + 1] = o[1];
            out[base + 2] = o[2];
        }
    }
}

// ---------------- Fallback kernels (ws too small): R1 pipeline ----------------
__global__ __launch_bounds__(256) void k_posegemm(const bf16* __restrict__ wspf,
        const bf16* __restrict__ wspdt, float* __restrict__ dout) {
    const ushort_t* pf  = (const ushort_t*)wspf;
    const ushort_t* pdt = (const ushort_t*)wspdt;
    int lane = threadIdx.x & 63;
    int wave = threadIdx.x >> 6;
    int l15 = lane & 15, quad = lane >> 4;
    int m0 = blockIdx.y * 32;
    int n0 = blockIdx.x * 256 + wave * 64;
    float4v acc[2][4] = {};
    for (int c = 0; c < 7; c++) {
        short8 a[2], bb[4];
#pragma unroll
        for (int mf = 0; mf < 2; mf++)
            a[mf] = *reinterpret_cast<const short8*>(pf + (m0 + mf*16 + l15)*KPAD + c*32 + quad*8);
#pragma unroll
        for (int nf = 0; nf < 4; nf++)
            bb[nf] = *reinterpret_cast<const short8*>(pdt + (n0 + nf*16 + l15)*KPAD + c*32 + quad*8);
#pragma unroll
        for (int mf = 0; mf < 2; mf++)
#pragma unroll
            for (int nf = 0; nf < 4; nf++)
                acc[mf][nf] = __builtin_amdgcn_mfma_f32_16x16x32_bf16(a[mf], bb[nf], acc[mf][nf], 0, 0, 0);
    }
#pragma unroll
    for (int mf = 0; mf < 2; mf++)
#pragma unroll
        for (int nf = 0; nf < 4; nf++) {
            int col = n0 + nf*16 + l15;
            if (col < NCOL) {
#pragma unroll
                for (int r = 0; r < 4; r++) {
                    int row = m0 + mf*16 + quad*4 + r;
                    dout[row*NCOL + col] = acc[mf][nf][r];
                }
            }
        }
}

__global__ __launch_bounds__(256) void k_lbs(const float* __restrict__ betas,
        const float* __restrict__ sd, const float* __restrict__ vt,
        const float* __restrict__ lbs, const float* __restrict__ Amat,
        float* __restrict__ out) {
    int tid = threadIdx.x;
    int v = blockIdx.x*256 + tid;
    if (v >= VDIM) return;
    int b0 = blockIdx.y * NB;
    float w[24];
    {
        const float4v* W4 = reinterpret_cast<const float4v*>(lbs + v*24);
#pragma unroll
        for (int q = 0; q < 6; q++) {
            float4v x = W4[q];
#pragma unroll
            for (int e = 0; e < 4; e++) w[q*4+e] = x[e];
        }
    }
    float vtv[3];
#pragma unroll
    for (int m = 0; m < 3; m++) vtv[m] = vt[v*3 + m];
    float sdv[30];
#pragma unroll
    for (int i = 0; i < 30; i++) sdv[i] = sd[v*30 + i];
    float* vsh = out + OUT_VSHAPED;
#pragma unroll 1
    for (int bb = 0; bb < NB; bb++) {
        int b = b0 + bb;
        const float* __restrict__ Ab = Amat + (size_t)b*384;
        float T[12];
#pragma unroll
        for (int e = 0; e < 12; e++) T[e] = 0.f;
#pragma unroll
        for (int j = 0; j < 24; j++) {
#pragma unroll
            for (int e = 0; e < 12; e++)
                T[e] = fmaf(w[j], Ab[j*16 + e], T[e]);
        }
        float vs[3];
#pragma unroll
        for (int m = 0; m < 3; m++) {
            float s = vtv[m];
#pragma unroll
            for (int l = 0; l < 10; l++) s += betas[b*10 + l] * sdv[m*10 + l];
            vs[m] = s;
        }
        int base = b*NCOL + v*3;
        float vp0 = vs[0] + vsh[base + 0];
        float vp1 = vs[1] + vsh[base + 1];
        float vp2 = vs[2] + vsh[base + 2];
#pragma unroll
        for (int m = 0; m < 3; m++) {
            float o = T[m*4+3] + T[m*4]*vp0 + T[m*4+1]*vp1 + T[m*4+2]*vp2;
            out[base + m] = o;
            vsh[base + m] = vs[m];
        }
    }
}

extern "C" void kernel_launch(void* const* d_in, const int* in_sizes, int n_in,
                              void* d_out, int out_size, void* d_ws, size_t ws_size,
                              hipStream_t stream) {
    const float *betas = nullptr, *pose = nullptr, *vt = nullptr, *sd = nullptr,
                *pd = nullptr, *jreg = nullptr, *lbs = nullptr;
    const int* parents = nullptr;
    for (int i = 0; i < n_in; i++) {
        switch (in_sizes[i]) {
            case 10240:   betas = (const float*)d_in[i]; break;      // (1024,10)
            case 73728:   pose  = (const float*)d_in[i]; break;      // (1024,72)
            case 20670:   vt    = (const float*)d_in[i]; break;      // (1,6890,3)
            case 206700:  sd    = (const float*)d_in[i]; break;      // (6890,3,10)
            case 4278690: pd    = (const float*)d_in[i]; break;      // (207,20670)
            case 24:      parents = (const int*)d_in[i]; break;      // (24,)
            case 165360:                                             // (24,6890)/(6890,24)
                if (!jreg) jreg = (const float*)d_in[i];
                else       lbs  = (const float*)d_in[i];
                break;
            default: break;
        }
    }
    float* out = (float*)d_out;
    if (d_ws && ws_size >= (size_t)WS_NEED) {
        // Main path: scratch in workspace; fused all-MFMA GEMM+LBS.
        bf16*     ws_pdt  = (bf16*)((char*)d_ws + WSB_PDT);
        bf16*     ws_pf   = (bf16*)((char*)d_ws + WSB_PF);
        float*    ws_jtjs = (float*)((char*)d_ws + WSB_JTJS);
        ushort_t* ws_whi  = (ushort_t*)((char*)d_ws + WSB_WHI);
        ushort_t* ws_wlo  = (ushort_t*)((char*)d_ws + WSB_WLO);
        ushort_t* ws_ahi  = (ushort_t*)((char*)d_ws + WSB_AHI);
        ushort_t* ws_alo  = (ushort_t*)((char*)d_ws + WSB_ALO);
        k_prep2<<<3156, 256, 0, stream>>>(jreg, vt, sd, lbs, pd, ws_jtjs,
                                          ws_whi, ws_wlo, ws_pdt);
        k_pose<<<BDIM/4, 256, 0, stream>>>(betas, pose, parents, ws_jtjs, out, ws_pf,
                                           ws_ahi, ws_alo);
        k_gemmlbs<<<108*32, 256, 0, stream>>>(ws_pf, ws_pdt, betas, sd, vt,
                                              ws_whi, ws_wlo, ws_ahi, ws_alo, out);
    } else {
        // Fallback (R1 pipeline): scratch inside the verts region of d_out.
        bf16*  ws_pdt  = (bf16*)(out + SCRF_PDT);
        bf16*  ws_pf   = (bf16*)(out + SCRF_PF);
        float* ws_jtjs = out + SCRF_JTJS;
        k_prep2<<<3156, 256, 0, stream>>>(jreg, vt, sd, lbs, pd, ws_jtjs,
                                          nullptr, nullptr, ws_pdt);
        k_pose<<<BDIM/4, 256, 0, stream>>>(betas, pose, parents, ws_jtjs, out, ws_pf,
                                           nullptr, nullptr);
        k_posegemm<<<dim3(81, 32), 256, 0, stream>>>(ws_pf, ws_pdt, out + OUT_VSHAPED);
        k_lbs<<<dim3(27, BDIM/NB), 256, 0, stream>>>(betas, sd, vt, lbs, out + OUT_A, out);
    }
}